// Round 6
// baseline (613.615 us; speedup 1.0000x reference)
//
#include <hip/hip_runtime.h>

// GAT 3-layer forward on MI355X — round 18 (= round 17 resubmitted; container infra
// failure last round, no measurement). Theory unchanged:
//  (1) hist_pack_k 68us @ VALUBusy 0.6%: 1.6M device-scope atomicAdd(&counts[d])
//      serialize at the LLC (WRITE_SIZE 56MB of atomic write-amplification).
//      FIX: drop CSR row padding (aggregates already zero-guard slots >= deg, so
//      over-reading into the next node's run is harmless given a zeroed 64-int
//      tail). Then rsp = bucketStart (from bhist scan, already computed) + local
//      in-bucket scan, and fscatter computes counts+rsp itself from its ebuf
//      segment (LDS hist + 256-wide LDS scan, coalesced writes). Global count
//      atomics and the counts-scan launches are GONE.
//  (2) gemm_bf16 L1 68us @ MfmaUtil 7.4%, Occupancy 12.8%: only 1250 waves (R=5),
//      latency-bound. FIX: R=1 -> 6250 waves (~24/CU); B stays L1/L2-resident.

typedef __attribute__((ext_vector_type(8))) short s8v;
typedef __attribute__((ext_vector_type(4))) float f4v;
typedef __attribute__((ext_vector_type(2))) float f2v;
typedef __attribute__((ext_vector_type(2))) _Float16 h2;
typedef __attribute__((ext_vector_type(4))) _Float16 h4;

__device__ __forceinline__ unsigned short f2bf(float f) {
  unsigned int x = __float_as_uint(f);
  x += 0x7fffu + ((x >> 16) & 1u);          // RTNE
  return (unsigned short)(x >> 16);
}
__device__ __forceinline__ float bf2f(unsigned short u) {
  return __uint_as_float(((unsigned int)u) << 16);
}
__device__ __forceinline__ unsigned short f2h(float f) {
  _Float16 h = (_Float16)f;
  return __builtin_bit_cast(unsigned short, h);
}
__device__ __forceinline__ unsigned char f2fp8(float v) {
  return (unsigned char)(__builtin_amdgcn_cvt_pk_fp8_f32(v, v, 0, false) & 0xff);
}
__device__ __forceinline__ float lrelu(float x) { return fmaxf(x, 0.2f * x); }
__device__ __forceinline__ float elu1(float x) { return x > 0.f ? x : __expf(x) - 1.f; }

// ---------------- fused bucket histogram + weight pack (one launch) ----------------
__device__ __forceinline__ void pack_one(const float* W, const float* al, const float* ar,
                                         const float* resW, unsigned short* out,
                                         int K, int M, int BF, int H, int RES0, int t) {
  int c = t / K, k = t - c * K;
  float v = 0.f;
  if (c < BF) {
    v = W[k * BF + c];
  } else if (c < BF + H) {
    int h = c - BF;
    float s = 0.f;
    for (int d = 0; d < 32; d++) s += W[k * BF + h * 32 + d] * al[h * 32 + d];
    v = s;
  } else if (c < BF + 2 * H) {
    int h = c - BF - H;
    float s = 0.f;
    for (int d = 0; d < 32; d++) s += W[k * BF + h * 32 + d] * ar[h * 32 + d];
    v = s;
  } else if (c >= RES0) {
    v = resW[k * (M - RES0) + (c - RES0)];
  }
  unsigned short hi = f2bf(v);
  out[c * K + k] = hi;
  out[M * K + c * K + k] = f2bf(v - bf2f(hi));
}

__global__ __launch_bounds__(256) void hist_pack_k(const int* __restrict__ dst,
                                                   int* __restrict__ bhist, int E, int NB, int chunk, int P2B,
                                                   const float* __restrict__ W0, const float* __restrict__ al0,
                                                   const float* __restrict__ ar0,
                                                   const float* __restrict__ W1, const float* __restrict__ al1,
                                                   const float* __restrict__ ar1, const float* __restrict__ resW1,
                                                   const float* __restrict__ W2, const float* __restrict__ al2,
                                                   const float* __restrict__ ar2, const float* __restrict__ resW2,
                                                   unsigned short* __restrict__ w0t, unsigned short* __restrict__ w1t,
                                                   unsigned short* __restrict__ w2t) {
  if ((int)blockIdx.x < P2B) {
    __shared__ int h[512];
    for (int b = threadIdx.x; b < NB; b += 256) h[b] = 0;
    __syncthreads();
    int e0 = blockIdx.x * chunk;
    int e1 = min(E, e0 + chunk);
    for (int e = e0 + threadIdx.x; e < e1; e += 256) atomicAdd(&h[dst[e] >> 8], 1);
    __syncthreads();
    for (int b = threadIdx.x; b < NB; b += 256)
      bhist[(size_t)b * P2B + blockIdx.x] = h[b];
  } else {
    const int n0 = 144 * 64, n1 = 272 * 128, n2 = 80 * 128;
    int t = ((int)blockIdx.x - P2B) * 256 + threadIdx.x;
    if (t < n0) {
      pack_one(W0, al0, ar0, nullptr, w0t, 64, 144, 128, 4, 144, t);
    } else if (t < n0 + n1) {
      pack_one(W1, al1, ar1, resW1, w1t, 128, 272, 128, 4, 144, t - n0);
    } else if (t < n0 + n1 + n2) {
      pack_one(W2, al2, ar2, resW2, w2t, 128, 80, 32, 1, 48, t - n0 - n1);
    }
  }
}

// ---------------- bucket-segment table scan (two phases) ----------------
__global__ __launch_bounds__(256) void pscan1(int* __restrict__ arr, int* __restrict__ bsum, int Nn) {
  __shared__ int s[256];
  int t = threadIdx.x;
  int base = blockIdx.x * 1024 + t * 4;
  int v0 = (base + 0 < Nn) ? arr[base + 0] : 0;
  int v1 = (base + 1 < Nn) ? arr[base + 1] : 0;
  int v2 = (base + 2 < Nn) ? arr[base + 2] : 0;
  int v3 = (base + 3 < Nn) ? arr[base + 3] : 0;
  s[t] = v0 + v1 + v2 + v3;
  __syncthreads();
  for (int off = 1; off < 256; off <<= 1) {
    int xv = (t >= off) ? s[t - off] : 0;
    __syncthreads();
    s[t] += xv;
    __syncthreads();
  }
  int excl = t ? s[t - 1] : 0;
  if (t == 255) bsum[blockIdx.x] = s[255];
  if (base + 0 < Nn) { arr[base + 0] = excl; excl += v0; }
  if (base + 1 < Nn) { arr[base + 1] = excl; excl += v1; }
  if (base + 2 < Nn) { arr[base + 2] = excl; excl += v2; }
  if (base + 3 < Nn) { arr[base + 3] = excl; }
}

__global__ __launch_bounds__(256) void pscan2(int* __restrict__ arr, const int* __restrict__ bsum,
                                              int Nn, int nb) {
  __shared__ int s[256];
  int t = threadIdx.x;
  s[t] = (t < nb) ? bsum[t] : 0;
  __syncthreads();
  for (int off = 1; off < 256; off <<= 1) {
    int xv = (t >= off) ? s[t - off] : 0;
    __syncthreads();
    s[t] += xv;
    __syncthreads();
  }
  int bb = blockIdx.x;
  int pref = bb ? s[bb - 1] : 0;
  if (pref != 0) {
    int base = bb * 1024 + t * 4;
    if (base + 0 < Nn) arr[base + 0] += pref;
    if (base + 1 < Nn) arr[base + 1] += pref;
    if (base + 2 < Nn) arr[base + 2] += pref;
    if (base + 3 < Nn) arr[base + 3] += pref;
  }
}

// ---------------- pass 2: scatter edges into private (block,bucket) segments --------
// ebuf entry: (src << 8) | (dst & 255) — 25 bits used.
__global__ __launch_bounds__(256) void bscatter_k(const int* __restrict__ src, const int* __restrict__ dst,
                                                  const int* __restrict__ seg, unsigned int* __restrict__ ebuf,
                                                  int E, int NB, int chunk) {
  __shared__ int cur[512];
  for (int b = threadIdx.x; b < NB; b += 256)
    cur[b] = seg[(size_t)b * gridDim.x + blockIdx.x];
  __syncthreads();
  int e0 = blockIdx.x * chunk;
  int e1 = min(E, e0 + chunk);
  for (int e = e0 + threadIdx.x; e < e1; e += 256) {
    int d = dst[e];
    int pos = atomicAdd(&cur[d >> 8], 1);
    ebuf[pos] = ((unsigned int)src[e] << 8) | (unsigned int)(d & 255);
  }
}

// ---------------- pass 3: per-bucket final scatter + counts/rsp emission ------------
// One block per 256-node bucket. Computes per-node degree (LDS hist of its ebuf
// segment), local exclusive scan -> rsp = bucketStart + localExcl (UNPADDED rows),
// writes counts+rsp coalesced, then scatters csr_src via LDS cursors.
__global__ __launch_bounds__(256) void fscatter_k(const unsigned int* __restrict__ ebuf,
                                                  const int* __restrict__ seg,
                                                  int* __restrict__ csr_src,
                                                  int* __restrict__ counts, int* __restrict__ rsp,
                                                  int E, int NB, int P2B, int Nn) {
  __shared__ int cnt[256];
  __shared__ int sc[256];
  __shared__ int cur[256];
  int b = blockIdx.x;
  int t = threadIdx.x;
  cnt[t] = 0;
  __syncthreads();
  int bstart = seg[(size_t)b * P2B];
  int bend = (b + 1 < NB) ? seg[(size_t)(b + 1) * P2B] : E;
  for (int e = bstart + t; e < bend; e += 256)
    atomicAdd(&cnt[ebuf[e] & 255u], 1);
  __syncthreads();
  int v = cnt[t];
  sc[t] = v;
  __syncthreads();
  for (int off = 1; off < 256; off <<= 1) {
    int xv = (t >= off) ? sc[t - off] : 0;
    __syncthreads();
    sc[t] += xv;
    __syncthreads();
  }
  int base = bstart + (t ? sc[t - 1] : 0);
  int node = (b << 8) + t;
  if (node < Nn) { counts[node] = v; rsp[node] = base; }
  cur[t] = base;
  __syncthreads();
  for (int e = bstart + t; e < bend; e += 256) {
    unsigned int sd = ebuf[e];
    int pos = atomicAdd(&cur[sd & 255u], 1);
    csr_src[pos] = (int)(sd >> 8);
  }
}

// ---------------- GEMM: A[N,K] @ Bt[M,K](bf16 hi+lo); cmw fold computed in-kernel ----
template <int K, int M, int R, int BF, int H, int RES0, bool AF32, bool CMW>
__global__ __launch_bounds__(256) void gemm_bf16(const void* __restrict__ Av,
                                                 const unsigned short* __restrict__ Bt,
                                                 const float* __restrict__ colsum, float invN,
                                                 unsigned char* __restrict__ feat8,
                                                 float* __restrict__ el, float* __restrict__ er,
                                                 unsigned short* __restrict__ resh, int nRowTiles) {
  __shared__ float cmw_s[M];
  if constexpr (CMW) {
    // rank-1 PairNorm fold: cmw[c] = invN * sum_k colsum[k]*(Whi[c,k]+Wlo[c,k])
    for (int cc = threadIdx.x; cc < M; cc += 256) {
      float s = 0.f;
      for (int k = 0; k < K; k++)
        s += colsum[k] * (bf2f(Bt[cc * K + k]) + bf2f(Bt[(size_t)M * K + cc * K + k]));
      cmw_s[cc] = s * invN;
    }
    __syncthreads();   // before any early return: all waves participate
  }
  int wv = (int)((blockIdx.x * blockDim.x + threadIdx.x) >> 6);
  int tile0 = wv * R;
  if (tile0 >= nRowTiles) return;
  int lane = threadIdx.x & 63;
  int r = lane & 15, q = lane >> 4;
  s8v afrag[R][K / 32];
#pragma unroll
  for (int rr = 0; rr < R; rr++) {
    if constexpr (AF32) {
      const float* arow = (const float*)Av + (size_t)((tile0 + rr) * 16 + r) * K + q * 8;
#pragma unroll
      for (int kk = 0; kk < K / 32; kk++) {
        s8v v;
#pragma unroll
        for (int j = 0; j < 8; j++) v[j] = (short)f2bf(arow[kk * 32 + j]);
        afrag[rr][kk] = v;
      }
    } else {
      const unsigned short* arow = (const unsigned short*)Av + (size_t)((tile0 + rr) * 16 + r) * K + q * 8;
#pragma unroll
      for (int kk = 0; kk < K / 32; kk++) afrag[rr][kk] = *(const s8v*)(arow + kk * 32);
    }
  }
#pragma unroll
  for (int ct = 0; ct < M / 16; ct++) {
    const unsigned short* brow = Bt + (size_t)(ct * 16 + r) * K + q * 8;
    s8v bhi[K / 32], blo[K / 32];
#pragma unroll
    for (int kk = 0; kk < K / 32; kk++) {
      bhi[kk] = *(const s8v*)(brow + kk * 32);
      blo[kk] = *(const s8v*)(brow + (size_t)M * K + kk * 32);
    }
    int col = ct * 16 + r;
    float cmwv = 0.f;
    if constexpr (CMW) cmwv = cmw_s[col];
#pragma unroll
    for (int rr = 0; rr < R; rr++) {
      f4v acc = {0.f, 0.f, 0.f, 0.f};
#pragma unroll
      for (int kk = 0; kk < K / 32; kk++) {
        acc = __builtin_amdgcn_mfma_f32_16x16x32_bf16(afrag[rr][kk], bhi[kk], acc, 0, 0, 0);
        acc = __builtin_amdgcn_mfma_f32_16x16x32_bf16(afrag[rr][kk], blo[kk], acc, 0, 0, 0);
      }
      int row0 = (tile0 + rr) * 16 + q * 4;
#pragma unroll
      for (int i = 0; i < 4; i++) {
        float v = acc[i] - cmwv;
        size_t row = (size_t)(row0 + i);
        if (col < BF) {
          feat8[row * BF + col] = f2fp8(v);
        } else if (col < BF + H) {
          el[row * H + (col - BF)] = v;
        } else if (col < BF + 2 * H) {
          er[row * H + (col - BF - H)] = v;
        } else if (RES0 < M && col >= RES0) {
          resh[row * (M - RES0) + (col - RES0)] = f2h(v);
        }
      }
    }
  }
}

// ---------------- fused single-pass aggregation H=4 (fp8 feat table) ----------------
// R12 memory structure (MLP=16) + pipelined el-gather. UNPADDED rows: slots >= deg
// read into the next node's run (or the zeroed csr tail) — guarded to contribute 0.
template <int MODE>
__global__ __launch_bounds__(256) void aggregate4(const unsigned char* __restrict__ feat8,
                                                  const float* __restrict__ el4,
                                                  const float* __restrict__ er4,
                                                  const int* __restrict__ csr_src,
                                                  const int* __restrict__ rsp,
                                                  const int* __restrict__ counts,
                                                  const unsigned short* __restrict__ resh,
                                                  unsigned short* __restrict__ vbf,
                                                  float* __restrict__ rnrm, int Nn) {
  int n = (int)((blockIdx.x * blockDim.x + threadIdx.x) >> 6);
  if (n >= Nn) return;
  int lane = threadIdx.x & 63;
  int start = __builtin_amdgcn_readfirstlane(rsp[n]);
  int deg = __builtin_amdgcn_readfirstlane(counts[n]);
  int chunks = (deg + 15) >> 4;
  int slot = lane >> 2, h = lane & 3;
  float ern = er4[(size_t)n * 4 + h];
  int hl = lane >> 4;                        // head of lane's dims (dims 2l..2l+1)
  unsigned dby = (unsigned)lane << 1;        // byte offset into 128B fp8 row
  f2v a01 = {0.f, 0.f};
  float dsum = 0.f;
  // prologue: chunk 0's phase-A gather
  float elv = el4[(size_t)csr_src[start + slot] * 4 + h];
  for (int c = 0; c < chunks; c++) {
    const int* csp = csr_src + start + (c << 4);
    // batch all 16 csr reads (wave-uniform -> scalar loads, 16 feat loads in flight)
    int sj[16];
#pragma unroll
    for (int j = 0; j < 16; j++) sj[j] = csp[j];
    // phase A from pipelined gather
    float e = elv + ern;
    float exv = (((c << 4) + slot) < deg) ? __expf(fmaxf(e, 0.2f * e)) : 0.f;
    dsum += exv;
    // prefetch next chunk's gather — hides under this chunk's FMA phase
    if (c + 1 < chunks) elv = el4[(size_t)csp[16 + slot] * 4 + h];
#pragma unroll
    for (int j = 0; j < 16; j++) {
      float aw = __shfl(exv, (j << 2) | hl);
      unsigned short u = *(const unsigned short*)(feat8 + (((unsigned)sj[j] << 7) + dby));
      f2v fv = __builtin_amdgcn_cvt_pk_f32_fp8((int)u, false);
      f2v aw2 = {aw, aw};
      a01 = __builtin_elementwise_fma(fv, aw2, a01);
    }
  }
  // per-head denominator totals: after butterfly, lane l holds head (l&3) total
#pragma unroll
  for (int off = 4; off < 64; off <<= 1) dsum += __shfl_xor(dsum, off);
  float inv = dsum > 0.f ? 1.f / dsum : 0.f;
  float invh = __shfl(inv, hl);
  float v0, v1;
  if (MODE == 1) {
    h2 rr = *(const h2*)(resh + (size_t)n * 128 + lane * 2);
    v0 = elu1(elu1(a01[0] * invh + (float)rr[0]));
    v1 = elu1(elu1(a01[1] * invh + (float)rr[1]));
  } else {
    v0 = elu1(a01[0] * invh);
    v1 = elu1(a01[1] * invh);
  }
  float ss = v0 * v0 + v1 * v1;
#pragma unroll
  for (int off = 1; off < 64; off <<= 1) ss += __shfl_xor(ss, off);
  float rn = sqrtf(1e-6f + ss);
  float ri = 1.f / rn;
  unsigned int pk = (unsigned int)f2bf(v0 * ri) | ((unsigned int)f2bf(v1 * ri) << 16);
  *(unsigned int*)((char*)vbf + ((size_t)n << 8) + (lane << 2)) = pk;
  if (lane == 0) rnrm[n] = rn;
}

// ---------------- fused single-pass aggregation H=1 (layer 2, fp8 table) ----------------
__global__ __launch_bounds__(256) void aggregate1(const unsigned char* __restrict__ feat8,
                                                  const float* __restrict__ el1,
                                                  const float* __restrict__ er1,
                                                  const int* __restrict__ csr_src,
                                                  const int* __restrict__ rsp,
                                                  const int* __restrict__ counts,
                                                  const unsigned short* __restrict__ res2h,
                                                  float* __restrict__ out2, int Nn) {
  int n = (int)((blockIdx.x * blockDim.x + threadIdx.x) >> 6);
  if (n >= Nn) return;
  int lane = threadIdx.x & 63;
  int start = __builtin_amdgcn_readfirstlane(rsp[n]);
  int deg = __builtin_amdgcn_readfirstlane(counts[n]);
  int chunks = (deg + 15) >> 4;
  int l16 = lane & 15;
  float ern = er1[n];
  int g = lane >> 3;                          // 8 edge groups (2 edges each per chunk)
  unsigned dofs4 = (unsigned)(lane & 7) << 2; // byte offset into 32B fp8 row
  f2v acc01 = {0.f, 0.f}, acc23 = {0.f, 0.f};
  float dsum = 0.f;
  // prologue: chunk 0's src + gather
  int sA = csr_src[start + l16];
  float elv = el1[sA];
  for (int c = 0; c < chunks; c++) {
    const int* csp = csr_src + start + (c << 4);
    float exv = (((c << 4) + l16) < deg) ? __expf(lrelu(elv + ern)) : 0.f;
    dsum += exv;
    int sAc = sA;                              // current chunk's src (address shuffles)
    if (c + 1 < chunks) {
      sA = csp[16 + l16];
      elv = el1[sA];
    }
#pragma unroll
    for (int t = 0; t < 2; t++) {
      int j = (t << 3) + g;
      int sj = __shfl(sAc, j);
      float aw = __shfl(exv, j);
      f2v aw2 = {aw, aw};
      unsigned int u = *(const unsigned int*)(feat8 + (((unsigned)sj << 5) + dofs4));
      f2v fa = __builtin_amdgcn_cvt_pk_f32_fp8((int)u, false);
      f2v fb = __builtin_amdgcn_cvt_pk_f32_fp8((int)u, true);
      acc01 = __builtin_elementwise_fma(fa, aw2, acc01);
      acc23 = __builtin_elementwise_fma(fb, aw2, acc23);
    }
  }
#pragma unroll
  for (int off = 1; off < 16; off <<= 1) dsum += __shfl_xor(dsum, off);
  float inv = dsum > 0.f ? 1.f / dsum : 0.f;
#pragma unroll
  for (int off = 8; off < 64; off <<= 1) {
    acc01[0] += __shfl_xor(acc01[0], off);
    acc01[1] += __shfl_xor(acc01[1], off);
    acc23[0] += __shfl_xor(acc23[0], off);
    acc23[1] += __shfl_xor(acc23[1], off);
  }
  if (lane < 8) {
    h4 rr = *(const h4*)(res2h + (size_t)n * 32 + (lane << 2));
    float4 o;
    o.x = acc01[0] * inv + (float)rr[0];
    o.y = acc01[1] * inv + (float)rr[1];
    o.z = acc23[0] * inv + (float)rr[2];
    o.w = acc23[1] * inv + (float)rr[3];
    *(float4*)(out2 + (size_t)n * 32 + (lane << 2)) = o;
  }
}

// ---------------- colsum of raw v = vbf * rnrm (PairNorm colmean numerator) ----------------
__global__ __launch_bounds__(256) void colsum_k(const unsigned short* __restrict__ vbf,
                                                const float* __restrict__ rnrm,
                                                float* __restrict__ colsum, int Nn) {
  __shared__ float ls[256];
  int tid = threadIdx.x;
  int c = tid & 127, rsub = tid >> 7;
  float cs = 0.f;
  for (int r = blockIdx.x * 2 + rsub; r < Nn; r += gridDim.x * 2)
    cs += bf2f(vbf[(size_t)r * 128 + c]) * rnrm[r];
  ls[tid] = cs;
  __syncthreads();
  if (tid < 128) atomicAdd(&colsum[tid], ls[tid] + ls[tid + 128]);
}

// ---------------- final: mean over nodes of out2 ----------------
__global__ __launch_bounds__(256) void final_reduce(const float* __restrict__ out2,
                                                    float* __restrict__ outsum, int Nn) {
  __shared__ float ls[32];
  if (threadIdx.x < 32) ls[threadIdx.x] = 0.f;
  __syncthreads();
  int d = threadIdx.x & 31, rl = threadIdx.x >> 5;
  float acc = 0.f;
  for (int n = blockIdx.x * 8 + rl; n < Nn; n += gridDim.x * 8)
    acc += out2[(size_t)n * 32 + d];
  atomicAdd(&ls[d], acc);
  __syncthreads();
  if (threadIdx.x < 32) atomicAdd(&outsum[threadIdx.x], ls[threadIdx.x]);
}

__global__ void finalize_k(const float* __restrict__ outsum, float* __restrict__ out, float invN) {
  int t = threadIdx.x;
  if (t < 32) out[t] = outsum[t] * invN;
}

// ---------------- launcher ----------------
extern "C" void kernel_launch(void* const* d_in, const int* in_sizes, int n_in,
                              void* d_out, int out_size, void* d_ws, size_t ws_size,
                              hipStream_t stream) {
  const float* x     = (const float*)d_in[0];
  const int*   src   = (const int*)d_in[1];
  const int*   dst   = (const int*)d_in[2];
  const float* W0    = (const float*)d_in[3];
  const float* al0   = (const float*)d_in[4];
  const float* ar0   = (const float*)d_in[5];
  const float* W1    = (const float*)d_in[6];
  const float* al1   = (const float*)d_in[7];
  const float* ar1   = (const float*)d_in[8];
  const float* resW1 = (const float*)d_in[9];
  const float* W2    = (const float*)d_in[10];
  const float* al2   = (const float*)d_in[11];
  const float* ar2   = (const float*)d_in[12];
  const float* resW2 = (const float*)d_in[13];
  const int N = in_sizes[0] / 64;   // 100000
  const int E = in_sizes[1];        // 1600000
  const float invN = 1.f / (float)N;
  const int Emax = E + 64;              // unpadded CSR + zeroed tail guard
  const int NB = (N + 255) >> 8;        // dst buckets of 256 nodes (391)
  const int P2B = 512;                  // histogram/scatter block count
  const int chunk = (E + P2B - 1) / P2B;
  const int segN = NB * P2B;            // bucket-major segment table length
  const int nbB = (segN + 1023) / 1024; // scan blocks for segment table (196)

  char* p = (char*)d_ws;
  auto alloc = [&](size_t bytes) { char* r = p; p += (bytes + 255) & ~(size_t)255; return r; };

  // zero-initialized region (small: reduction accumulators only)
  char* zbase = p;
  float* colsumA = (float*)alloc(512);
  float* colsumB = (float*)alloc(512);
  float* outsum  = (float*)alloc(128);
  size_t zbytes = (size_t)(p - zbase);

  int* counts = (int*)alloc((size_t)4 * N);     // written by fscatter
  int* rsp    = (int*)alloc((size_t)4 * N);     // written by fscatter (unpadded row starts)
  int* bsumB  = (int*)alloc(1024);
  int* bhist  = (int*)alloc((size_t)4 * segN);  // per-(bucket,block) counts -> seg (scanned in place)
  unsigned int* ebuf = (unsigned int*)alloc((size_t)4 * E);  // packed (src<<8)|(dst&255)
  int* csr_src = (int*)alloc((size_t)4 * Emax);
  unsigned char*  feat8 = (unsigned char*)alloc((size_t)N * 128);     // fp8 gather table
  unsigned short* vbf   = (unsigned short*)alloc((size_t)2 * N * 128);
  unsigned short* resh  = (unsigned short*)alloc((size_t)2 * N * 128);  // f16 residuals
  unsigned short* w0t = (unsigned short*)alloc((size_t)2 * 2 * 144 * 64);
  unsigned short* w1t = (unsigned short*)alloc((size_t)2 * 2 * 272 * 128);
  unsigned short* w2t = (unsigned short*)alloc((size_t)2 * 2 * 80 * 128);
  float* el4  = (float*)alloc((size_t)16 * N);
  float* er4  = (float*)alloc((size_t)16 * N);
  float* rnrm = (float*)alloc((size_t)4 * N);
  float* out2 = (float*)alloc((size_t)4 * N * 32);   // layer-2 output [N][32]

  hipMemsetAsync(zbase, 0, zbytes, stream);
  hipMemsetAsync(csr_src + E, 0, (size_t)4 * (Emax - E), stream);  // tail guard only

  // CSR build + weight pack: bucket hist/pack -> seg scan -> bucket scatter ->
  // final scatter (emits counts + rsp itself; no global count atomics anywhere)
  const int packTot = 144 * 64 + 272 * 128 + 80 * 128;   // 54272
  const int packBlocks = (packTot + 255) / 256;          // 212
  hist_pack_k<<<P2B + packBlocks, 256, 0, stream>>>(dst, bhist, E, NB, chunk, P2B,
                                                    W0, al0, ar0, W1, al1, ar1, resW1,
                                                    W2, al2, ar2, resW2, w0t, w1t, w2t);
  pscan1<<<nbB, 256, 0, stream>>>(bhist, bsumB, segN);
  pscan2<<<nbB, 256, 0, stream>>>(bhist, bsumB, segN, nbB);
  bscatter_k<<<P2B, 256, 0, stream>>>(src, dst, bhist, ebuf, E, NB, chunk);
  fscatter_k<<<NB, 256, 0, stream>>>(ebuf, bhist, csr_src, counts, rsp, E, NB, P2B, N);

  const int rowTiles = N / 16;                  // 6250
  const int gblocks = (rowTiles + 3) / 4;       // R=1: 6250 waves, 4/block
  const int aggblocks = (N + 3) / 4;            // wave per node

  // Layer 0 (A = x fp32, no colmean fold)
  gemm_bf16<64, 144, 1, 128, 4, 144, true, false><<<gblocks, 256, 0, stream>>>(
      x, w0t, nullptr, invN, feat8, el4, er4, nullptr, rowTiles);
  aggregate4<0><<<aggblocks, 256, 0, stream>>>(feat8, el4, er4, csr_src, rsp, counts, nullptr, vbf, rnrm, N);
  colsum_k<<<512, 256, 0, stream>>>(vbf, rnrm, colsumA, N);

  // Layer 1 (A = vbf, colmean folded in-kernel from colsumA)
  gemm_bf16<128, 272, 1, 128, 4, 144, false, true><<<gblocks, 256, 0, stream>>>(
      vbf, w1t, colsumA, invN, feat8, el4, er4, resh, rowTiles);
  aggregate4<1><<<aggblocks, 256, 0, stream>>>(feat8, el4, er4, csr_src, rsp, counts, resh, vbf, rnrm, N);
  colsum_k<<<512, 256, 0, stream>>>(vbf, rnrm, colsumB, N);

  // Layer 2 (A = vbf, colmean folded in-kernel from colsumB)
  gemm_bf16<128, 80, 1, 32, 1, 48, false, true><<<gblocks, 256, 0, stream>>>(
      vbf, w2t, colsumB, invN, feat8, el4, er4, resh, rowTiles);
  aggregate1<<<aggblocks, 256, 0, stream>>>(feat8, el4, er4, csr_src, rsp, counts, resh, out2, N);
  final_reduce<<<512, 256, 0, stream>>>(out2, outsum, N);
  finalize_k<<<1, 64, 0, stream>>>(outsum, (float*)d_out, invN);
}

// Round 7
// 552.707 us; speedup vs baseline: 1.1102x; 1.1102x over previous
//
#include <hip/hip_runtime.h>

// GAT 3-layer forward on MI355X — round 19.
// R18 post-mortem: CSR/atomic fix landed (hist_pack_k out of top-5, ~23us saved) but
// R=1 GEMM regressed 68->158us: B-load instruction count scales with wave count
// (each wave streams all of B), so R=1 did 5x the B-loads for the same MFMA work.
// R19: R=5 (B amortization restored) + column-group split CG (wave (rowGroup,cg)
// handles cts cg, cg+CG, ...) -> same total B traffic, CGx more waves for TLP.
// L0/L2: CG=2, L1: CG=4. Also: cmw fold moved back to a tiny standalone kernel —
// the in-GEMM prologue made every block redo a 272x128 dot sweep behind a barrier.
// CSR pipeline unchanged from R18 (no global count atomics; fscatter emits
// counts/rsp; unpadded rows with zero-guarded tail).

typedef __attribute__((ext_vector_type(8))) short s8v;
typedef __attribute__((ext_vector_type(4))) float f4v;
typedef __attribute__((ext_vector_type(2))) float f2v;
typedef __attribute__((ext_vector_type(2))) _Float16 h2;
typedef __attribute__((ext_vector_type(4))) _Float16 h4;

__device__ __forceinline__ unsigned short f2bf(float f) {
  unsigned int x = __float_as_uint(f);
  x += 0x7fffu + ((x >> 16) & 1u);          // RTNE
  return (unsigned short)(x >> 16);
}
__device__ __forceinline__ float bf2f(unsigned short u) {
  return __uint_as_float(((unsigned int)u) << 16);
}
__device__ __forceinline__ unsigned short f2h(float f) {
  _Float16 h = (_Float16)f;
  return __builtin_bit_cast(unsigned short, h);
}
__device__ __forceinline__ unsigned char f2fp8(float v) {
  return (unsigned char)(__builtin_amdgcn_cvt_pk_fp8_f32(v, v, 0, false) & 0xff);
}
__device__ __forceinline__ float lrelu(float x) { return fmaxf(x, 0.2f * x); }
__device__ __forceinline__ float elu1(float x) { return x > 0.f ? x : __expf(x) - 1.f; }

// ---------------- fused bucket histogram + weight pack (one launch) ----------------
__device__ __forceinline__ void pack_one(const float* W, const float* al, const float* ar,
                                         const float* resW, unsigned short* out,
                                         int K, int M, int BF, int H, int RES0, int t) {
  int c = t / K, k = t - c * K;
  float v = 0.f;
  if (c < BF) {
    v = W[k * BF + c];
  } else if (c < BF + H) {
    int h = c - BF;
    float s = 0.f;
    for (int d = 0; d < 32; d++) s += W[k * BF + h * 32 + d] * al[h * 32 + d];
    v = s;
  } else if (c < BF + 2 * H) {
    int h = c - BF - H;
    float s = 0.f;
    for (int d = 0; d < 32; d++) s += W[k * BF + h * 32 + d] * ar[h * 32 + d];
    v = s;
  } else if (c >= RES0) {
    v = resW[k * (M - RES0) + (c - RES0)];
  }
  unsigned short hi = f2bf(v);
  out[c * K + k] = hi;
  out[M * K + c * K + k] = f2bf(v - bf2f(hi));
}

__global__ __launch_bounds__(256) void hist_pack_k(const int* __restrict__ dst,
                                                   int* __restrict__ bhist, int E, int NB, int chunk, int P2B,
                                                   const float* __restrict__ W0, const float* __restrict__ al0,
                                                   const float* __restrict__ ar0,
                                                   const float* __restrict__ W1, const float* __restrict__ al1,
                                                   const float* __restrict__ ar1, const float* __restrict__ resW1,
                                                   const float* __restrict__ W2, const float* __restrict__ al2,
                                                   const float* __restrict__ ar2, const float* __restrict__ resW2,
                                                   unsigned short* __restrict__ w0t, unsigned short* __restrict__ w1t,
                                                   unsigned short* __restrict__ w2t) {
  if ((int)blockIdx.x < P2B) {
    __shared__ int h[512];
    for (int b = threadIdx.x; b < NB; b += 256) h[b] = 0;
    __syncthreads();
    int e0 = blockIdx.x * chunk;
    int e1 = min(E, e0 + chunk);
    for (int e = e0 + threadIdx.x; e < e1; e += 256) atomicAdd(&h[dst[e] >> 8], 1);
    __syncthreads();
    for (int b = threadIdx.x; b < NB; b += 256)
      bhist[(size_t)b * P2B + blockIdx.x] = h[b];
  } else {
    const int n0 = 144 * 64, n1 = 272 * 128, n2 = 80 * 128;
    int t = ((int)blockIdx.x - P2B) * 256 + threadIdx.x;
    if (t < n0) {
      pack_one(W0, al0, ar0, nullptr, w0t, 64, 144, 128, 4, 144, t);
    } else if (t < n0 + n1) {
      pack_one(W1, al1, ar1, resW1, w1t, 128, 272, 128, 4, 144, t - n0);
    } else if (t < n0 + n1 + n2) {
      pack_one(W2, al2, ar2, resW2, w2t, 128, 80, 32, 1, 48, t - n0 - n1);
    }
  }
}

// ---------------- bucket-segment table scan (two phases) ----------------
__global__ __launch_bounds__(256) void pscan1(int* __restrict__ arr, int* __restrict__ bsum, int Nn) {
  __shared__ int s[256];
  int t = threadIdx.x;
  int base = blockIdx.x * 1024 + t * 4;
  int v0 = (base + 0 < Nn) ? arr[base + 0] : 0;
  int v1 = (base + 1 < Nn) ? arr[base + 1] : 0;
  int v2 = (base + 2 < Nn) ? arr[base + 2] : 0;
  int v3 = (base + 3 < Nn) ? arr[base + 3] : 0;
  s[t] = v0 + v1 + v2 + v3;
  __syncthreads();
  for (int off = 1; off < 256; off <<= 1) {
    int xv = (t >= off) ? s[t - off] : 0;
    __syncthreads();
    s[t] += xv;
    __syncthreads();
  }
  int excl = t ? s[t - 1] : 0;
  if (t == 255) bsum[blockIdx.x] = s[255];
  if (base + 0 < Nn) { arr[base + 0] = excl; excl += v0; }
  if (base + 1 < Nn) { arr[base + 1] = excl; excl += v1; }
  if (base + 2 < Nn) { arr[base + 2] = excl; excl += v2; }
  if (base + 3 < Nn) { arr[base + 3] = excl; }
}

__global__ __launch_bounds__(256) void pscan2(int* __restrict__ arr, const int* __restrict__ bsum,
                                              int Nn, int nb) {
  __shared__ int s[256];
  int t = threadIdx.x;
  s[t] = (t < nb) ? bsum[t] : 0;
  __syncthreads();
  for (int off = 1; off < 256; off <<= 1) {
    int xv = (t >= off) ? s[t - off] : 0;
    __syncthreads();
    s[t] += xv;
    __syncthreads();
  }
  int bb = blockIdx.x;
  int pref = bb ? s[bb - 1] : 0;
  if (pref != 0) {
    int base = bb * 1024 + t * 4;
    if (base + 0 < Nn) arr[base + 0] += pref;
    if (base + 1 < Nn) arr[base + 1] += pref;
    if (base + 2 < Nn) arr[base + 2] += pref;
    if (base + 3 < Nn) arr[base + 3] += pref;
  }
}

// ---------------- pass 2: scatter edges into private (block,bucket) segments --------
// ebuf entry: (src << 8) | (dst & 255) — 25 bits used.
__global__ __launch_bounds__(256) void bscatter_k(const int* __restrict__ src, const int* __restrict__ dst,
                                                  const int* __restrict__ seg, unsigned int* __restrict__ ebuf,
                                                  int E, int NB, int chunk) {
  __shared__ int cur[512];
  for (int b = threadIdx.x; b < NB; b += 256)
    cur[b] = seg[(size_t)b * gridDim.x + blockIdx.x];
  __syncthreads();
  int e0 = blockIdx.x * chunk;
  int e1 = min(E, e0 + chunk);
  for (int e = e0 + threadIdx.x; e < e1; e += 256) {
    int d = dst[e];
    int pos = atomicAdd(&cur[d >> 8], 1);
    ebuf[pos] = ((unsigned int)src[e] << 8) | (unsigned int)(d & 255);
  }
}

// ---------------- pass 3: per-bucket final scatter + counts/rsp emission ------------
__global__ __launch_bounds__(256) void fscatter_k(const unsigned int* __restrict__ ebuf,
                                                  const int* __restrict__ seg,
                                                  int* __restrict__ csr_src,
                                                  int* __restrict__ counts, int* __restrict__ rsp,
                                                  int E, int NB, int P2B, int Nn) {
  __shared__ int cnt[256];
  __shared__ int sc[256];
  __shared__ int cur[256];
  int b = blockIdx.x;
  int t = threadIdx.x;
  cnt[t] = 0;
  __syncthreads();
  int bstart = seg[(size_t)b * P2B];
  int bend = (b + 1 < NB) ? seg[(size_t)(b + 1) * P2B] : E;
  for (int e = bstart + t; e < bend; e += 256)
    atomicAdd(&cnt[ebuf[e] & 255u], 1);
  __syncthreads();
  int v = cnt[t];
  sc[t] = v;
  __syncthreads();
  for (int off = 1; off < 256; off <<= 1) {
    int xv = (t >= off) ? sc[t - off] : 0;
    __syncthreads();
    sc[t] += xv;
    __syncthreads();
  }
  int base = bstart + (t ? sc[t - 1] : 0);
  int node = (b << 8) + t;
  if (node < Nn) { counts[node] = v; rsp[node] = base; }
  cur[t] = base;
  __syncthreads();
  for (int e = bstart + t; e < bend; e += 256) {
    unsigned int sd = ebuf[e];
    int pos = atomicAdd(&cur[sd & 255u], 1);
    csr_src[pos] = (int)(sd >> 8);
  }
}

// ---------------- cmw[col] = invN * colsum @ (W_hi + W_lo)  (rank-1 PairNorm fold) ----
__global__ __launch_bounds__(256) void cmw_k(const float* __restrict__ colsum,
                                             const unsigned short* __restrict__ wt,
                                             float* __restrict__ cmw, int K, int M, float invN) {
  int c = blockIdx.x * 256 + threadIdx.x;
  if (c >= M) return;
  float s = 0.f;
  for (int k = 0; k < K; k++)
    s += colsum[k] * (bf2f(wt[c * K + k]) + bf2f(wt[(size_t)M * K + c * K + k]));
  cmw[c] = s * invN;
}

// ---------------- GEMM: A[N,K] @ Bt[M,K](bf16 hi+lo), col-group split ----------------
// wave (rowGroup, cg): R row-tiles, cts cg, cg+CG, ... — B amortized over R rows,
// CG× more waves for TLP at the same total B traffic.
template <int K, int M, int R, int CG, int BF, int H, int RES0, bool AF32, bool CMW>
__global__ __launch_bounds__(256) void gemm_bf16(const void* __restrict__ Av,
                                                 const unsigned short* __restrict__ Bt,
                                                 const float* __restrict__ cmw,
                                                 unsigned char* __restrict__ feat8,
                                                 float* __restrict__ el, float* __restrict__ er,
                                                 unsigned short* __restrict__ resh, int nRowTiles) {
  int wv = (int)((blockIdx.x * blockDim.x + threadIdx.x) >> 6);
  int rowGroup = wv / CG;
  int cg = wv - rowGroup * CG;
  int tile0 = rowGroup * R;
  if (tile0 >= nRowTiles) return;
  int lane = threadIdx.x & 63;
  int r = lane & 15, q = lane >> 4;
  s8v afrag[R][K / 32];
#pragma unroll
  for (int rr = 0; rr < R; rr++) {
    if constexpr (AF32) {
      const float* arow = (const float*)Av + (size_t)((tile0 + rr) * 16 + r) * K + q * 8;
#pragma unroll
      for (int kk = 0; kk < K / 32; kk++) {
        s8v v;
#pragma unroll
        for (int j = 0; j < 8; j++) v[j] = (short)f2bf(arow[kk * 32 + j]);
        afrag[rr][kk] = v;
      }
    } else {
      const unsigned short* arow = (const unsigned short*)Av + (size_t)((tile0 + rr) * 16 + r) * K + q * 8;
#pragma unroll
      for (int kk = 0; kk < K / 32; kk++) afrag[rr][kk] = *(const s8v*)(arow + kk * 32);
    }
  }
  for (int ct = cg; ct < M / 16; ct += CG) {
    const unsigned short* brow = Bt + (size_t)(ct * 16 + r) * K + q * 8;
    s8v bhi[K / 32], blo[K / 32];
#pragma unroll
    for (int kk = 0; kk < K / 32; kk++) {
      bhi[kk] = *(const s8v*)(brow + kk * 32);
      blo[kk] = *(const s8v*)(brow + (size_t)M * K + kk * 32);
    }
    int col = ct * 16 + r;
    float cmwv = 0.f;
    if constexpr (CMW) cmwv = cmw[col];
#pragma unroll
    for (int rr = 0; rr < R; rr++) {
      f4v acc = {0.f, 0.f, 0.f, 0.f};
#pragma unroll
      for (int kk = 0; kk < K / 32; kk++) {
        acc = __builtin_amdgcn_mfma_f32_16x16x32_bf16(afrag[rr][kk], bhi[kk], acc, 0, 0, 0);
        acc = __builtin_amdgcn_mfma_f32_16x16x32_bf16(afrag[rr][kk], blo[kk], acc, 0, 0, 0);
      }
      int row0 = (tile0 + rr) * 16 + q * 4;
#pragma unroll
      for (int i = 0; i < 4; i++) {
        float v = acc[i] - cmwv;
        size_t row = (size_t)(row0 + i);
        if (col < BF) {
          feat8[row * BF + col] = f2fp8(v);
        } else if (col < BF + H) {
          el[row * H + (col - BF)] = v;
        } else if (col < BF + 2 * H) {
          er[row * H + (col - BF - H)] = v;
        } else if (RES0 < M && col >= RES0) {
          resh[row * (M - RES0) + (col - RES0)] = f2h(v);
        }
      }
    }
  }
}

// ---------------- fused single-pass aggregation H=4 (fp8 feat table) ----------------
// R12 memory structure (MLP=16) + pipelined el-gather. UNPADDED rows: slots >= deg
// read into the next node's run (or the zeroed csr tail) — guarded to contribute 0.
template <int MODE>
__global__ __launch_bounds__(256) void aggregate4(const unsigned char* __restrict__ feat8,
                                                  const float* __restrict__ el4,
                                                  const float* __restrict__ er4,
                                                  const int* __restrict__ csr_src,
                                                  const int* __restrict__ rsp,
                                                  const int* __restrict__ counts,
                                                  const unsigned short* __restrict__ resh,
                                                  unsigned short* __restrict__ vbf,
                                                  float* __restrict__ rnrm, int Nn) {
  int n = (int)((blockIdx.x * blockDim.x + threadIdx.x) >> 6);
  if (n >= Nn) return;
  int lane = threadIdx.x & 63;
  int start = __builtin_amdgcn_readfirstlane(rsp[n]);
  int deg = __builtin_amdgcn_readfirstlane(counts[n]);
  int chunks = (deg + 15) >> 4;
  int slot = lane >> 2, h = lane & 3;
  float ern = er4[(size_t)n * 4 + h];
  int hl = lane >> 4;                        // head of lane's dims (dims 2l..2l+1)
  unsigned dby = (unsigned)lane << 1;        // byte offset into 128B fp8 row
  f2v a01 = {0.f, 0.f};
  float dsum = 0.f;
  // prologue: chunk 0's phase-A gather
  float elv = el4[(size_t)csr_src[start + slot] * 4 + h];
  for (int c = 0; c < chunks; c++) {
    const int* csp = csr_src + start + (c << 4);
    // batch all 16 csr reads (wave-uniform -> scalar loads, 16 feat loads in flight)
    int sj[16];
#pragma unroll
    for (int j = 0; j < 16; j++) sj[j] = csp[j];
    // phase A from pipelined gather
    float e = elv + ern;
    float exv = (((c << 4) + slot) < deg) ? __expf(fmaxf(e, 0.2f * e)) : 0.f;
    dsum += exv;
    // prefetch next chunk's gather — hides under this chunk's FMA phase
    if (c + 1 < chunks) elv = el4[(size_t)csp[16 + slot] * 4 + h];
#pragma unroll
    for (int j = 0; j < 16; j++) {
      float aw = __shfl(exv, (j << 2) | hl);
      unsigned short u = *(const unsigned short*)(feat8 + (((unsigned)sj[j] << 7) + dby));
      f2v fv = __builtin_amdgcn_cvt_pk_f32_fp8((int)u, false);
      f2v aw2 = {aw, aw};
      a01 = __builtin_elementwise_fma(fv, aw2, a01);
    }
  }
  // per-head denominator totals: after butterfly, lane l holds head (l&3) total
#pragma unroll
  for (int off = 4; off < 64; off <<= 1) dsum += __shfl_xor(dsum, off);
  float inv = dsum > 0.f ? 1.f / dsum : 0.f;
  float invh = __shfl(inv, hl);
  float v0, v1;
  if (MODE == 1) {
    h2 rr = *(const h2*)(resh + (size_t)n * 128 + lane * 2);
    v0 = elu1(elu1(a01[0] * invh + (float)rr[0]));
    v1 = elu1(elu1(a01[1] * invh + (float)rr[1]));
  } else {
    v0 = elu1(a01[0] * invh);
    v1 = elu1(a01[1] * invh);
  }
  float ss = v0 * v0 + v1 * v1;
#pragma unroll
  for (int off = 1; off < 64; off <<= 1) ss += __shfl_xor(ss, off);
  float rn = sqrtf(1e-6f + ss);
  float ri = 1.f / rn;
  unsigned int pk = (unsigned int)f2bf(v0 * ri) | ((unsigned int)f2bf(v1 * ri) << 16);
  *(unsigned int*)((char*)vbf + ((size_t)n << 8) + (lane << 2)) = pk;
  if (lane == 0) rnrm[n] = rn;
}

// ---------------- fused single-pass aggregation H=1 (layer 2, fp8 table) ----------------
__global__ __launch_bounds__(256) void aggregate1(const unsigned char* __restrict__ feat8,
                                                  const float* __restrict__ el1,
                                                  const float* __restrict__ er1,
                                                  const int* __restrict__ csr_src,
                                                  const int* __restrict__ rsp,
                                                  const int* __restrict__ counts,
                                                  const unsigned short* __restrict__ res2h,
                                                  float* __restrict__ out2, int Nn) {
  int n = (int)((blockIdx.x * blockDim.x + threadIdx.x) >> 6);
  if (n >= Nn) return;
  int lane = threadIdx.x & 63;
  int start = __builtin_amdgcn_readfirstlane(rsp[n]);
  int deg = __builtin_amdgcn_readfirstlane(counts[n]);
  int chunks = (deg + 15) >> 4;
  int l16 = lane & 15;
  float ern = er1[n];
  int g = lane >> 3;                          // 8 edge groups (2 edges each per chunk)
  unsigned dofs4 = (unsigned)(lane & 7) << 2; // byte offset into 32B fp8 row
  f2v acc01 = {0.f, 0.f}, acc23 = {0.f, 0.f};
  float dsum = 0.f;
  // prologue: chunk 0's src + gather
  int sA = csr_src[start + l16];
  float elv = el1[sA];
  for (int c = 0; c < chunks; c++) {
    const int* csp = csr_src + start + (c << 4);
    float exv = (((c << 4) + l16) < deg) ? __expf(lrelu(elv + ern)) : 0.f;
    dsum += exv;
    int sAc = sA;                              // current chunk's src (address shuffles)
    if (c + 1 < chunks) {
      sA = csp[16 + l16];
      elv = el1[sA];
    }
#pragma unroll
    for (int t = 0; t < 2; t++) {
      int j = (t << 3) + g;
      int sj = __shfl(sAc, j);
      float aw = __shfl(exv, j);
      f2v aw2 = {aw, aw};
      unsigned int u = *(const unsigned int*)(feat8 + (((unsigned)sj << 5) + dofs4));
      f2v fa = __builtin_amdgcn_cvt_pk_f32_fp8((int)u, false);
      f2v fb = __builtin_amdgcn_cvt_pk_f32_fp8((int)u, true);
      acc01 = __builtin_elementwise_fma(fa, aw2, acc01);
      acc23 = __builtin_elementwise_fma(fb, aw2, acc23);
    }
  }
#pragma unroll
  for (int off = 1; off < 16; off <<= 1) dsum += __shfl_xor(dsum, off);
  float inv = dsum > 0.f ? 1.f / dsum : 0.f;
#pragma unroll
  for (int off = 8; off < 64; off <<= 1) {
    acc01[0] += __shfl_xor(acc01[0], off);
    acc01[1] += __shfl_xor(acc01[1], off);
    acc23[0] += __shfl_xor(acc23[0], off);
    acc23[1] += __shfl_xor(acc23[1], off);
  }
  if (lane < 8) {
    h4 rr = *(const h4*)(res2h + (size_t)n * 32 + (lane << 2));
    float4 o;
    o.x = acc01[0] * inv + (float)rr[0];
    o.y = acc01[1] * inv + (float)rr[1];
    o.z = acc23[0] * inv + (float)rr[2];
    o.w = acc23[1] * inv + (float)rr[3];
    *(float4*)(out2 + (size_t)n * 32 + (lane << 2)) = o;
  }
}

// ---------------- colsum of raw v = vbf * rnrm (PairNorm colmean numerator) ----------------
__global__ __launch_bounds__(256) void colsum_k(const unsigned short* __restrict__ vbf,
                                                const float* __restrict__ rnrm,
                                                float* __restrict__ colsum, int Nn) {
  __shared__ float ls[256];
  int tid = threadIdx.x;
  int c = tid & 127, rsub = tid >> 7;
  float cs = 0.f;
  for (int r = blockIdx.x * 2 + rsub; r < Nn; r += gridDim.x * 2)
    cs += bf2f(vbf[(size_t)r * 128 + c]) * rnrm[r];
  ls[tid] = cs;
  __syncthreads();
  if (tid < 128) atomicAdd(&colsum[tid], ls[tid] + ls[tid + 128]);
}

// ---------------- final: mean over nodes of out2 ----------------
__global__ __launch_bounds__(256) void final_reduce(const float* __restrict__ out2,
                                                    float* __restrict__ outsum, int Nn) {
  __shared__ float ls[32];
  if (threadIdx.x < 32) ls[threadIdx.x] = 0.f;
  __syncthreads();
  int d = threadIdx.x & 31, rl = threadIdx.x >> 5;
  float acc = 0.f;
  for (int n = blockIdx.x * 8 + rl; n < Nn; n += gridDim.x * 8)
    acc += out2[(size_t)n * 32 + d];
  atomicAdd(&ls[d], acc);
  __syncthreads();
  if (threadIdx.x < 32) atomicAdd(&outsum[threadIdx.x], ls[threadIdx.x]);
}

__global__ void finalize_k(const float* __restrict__ outsum, float* __restrict__ out, float invN) {
  int t = threadIdx.x;
  if (t < 32) out[t] = outsum[t] * invN;
}

// ---------------- launcher ----------------
extern "C" void kernel_launch(void* const* d_in, const int* in_sizes, int n_in,
                              void* d_out, int out_size, void* d_ws, size_t ws_size,
                              hipStream_t stream) {
  const float* x     = (const float*)d_in[0];
  const int*   src   = (const int*)d_in[1];
  const int*   dst   = (const int*)d_in[2];
  const float* W0    = (const float*)d_in[3];
  const float* al0   = (const float*)d_in[4];
  const float* ar0   = (const float*)d_in[5];
  const float* W1    = (const float*)d_in[6];
  const float* al1   = (const float*)d_in[7];
  const float* ar1   = (const float*)d_in[8];
  const float* resW1 = (const float*)d_in[9];
  const float* W2    = (const float*)d_in[10];
  const float* al2   = (const float*)d_in[11];
  const float* ar2   = (const float*)d_in[12];
  const float* resW2 = (const float*)d_in[13];
  const int N = in_sizes[0] / 64;   // 100000
  const int E = in_sizes[1];        // 1600000
  const float invN = 1.f / (float)N;
  const int Emax = E + 64;              // unpadded CSR + zeroed tail guard
  const int NB = (N + 255) >> 8;        // dst buckets of 256 nodes (391)
  const int P2B = 512;                  // histogram/scatter block count
  const int chunk = (E + P2B - 1) / P2B;
  const int segN = NB * P2B;            // bucket-major segment table length
  const int nbB = (segN + 1023) / 1024; // scan blocks for segment table (196)

  char* p = (char*)d_ws;
  auto alloc = [&](size_t bytes) { char* r = p; p += (bytes + 255) & ~(size_t)255; return r; };

  // zero-initialized region (small: reduction accumulators only)
  char* zbase = p;
  float* colsumA = (float*)alloc(512);
  float* colsumB = (float*)alloc(512);
  float* outsum  = (float*)alloc(128);
  size_t zbytes = (size_t)(p - zbase);

  int* counts = (int*)alloc((size_t)4 * N);     // written by fscatter
  int* rsp    = (int*)alloc((size_t)4 * N);     // written by fscatter (unpadded row starts)
  int* bsumB  = (int*)alloc(1024);
  int* bhist  = (int*)alloc((size_t)4 * segN);  // per-(bucket,block) counts -> seg (scanned in place)
  unsigned int* ebuf = (unsigned int*)alloc((size_t)4 * E);  // packed (src<<8)|(dst&255)
  int* csr_src = (int*)alloc((size_t)4 * Emax);
  unsigned char*  feat8 = (unsigned char*)alloc((size_t)N * 128);     // fp8 gather table
  unsigned short* vbf   = (unsigned short*)alloc((size_t)2 * N * 128);
  unsigned short* resh  = (unsigned short*)alloc((size_t)2 * N * 128);  // f16 residuals
  unsigned short* w0t = (unsigned short*)alloc((size_t)2 * 2 * 144 * 64);
  unsigned short* w1t = (unsigned short*)alloc((size_t)2 * 2 * 272 * 128);
  unsigned short* w2t = (unsigned short*)alloc((size_t)2 * 2 * 80 * 128);
  float* el4  = (float*)alloc((size_t)16 * N);
  float* er4  = (float*)alloc((size_t)16 * N);
  float* rnrm = (float*)alloc((size_t)4 * N);
  float* cmw1 = (float*)alloc(4 * 272);
  float* cmw2 = (float*)alloc(4 * 80);
  float* out2 = (float*)alloc((size_t)4 * N * 32);   // layer-2 output [N][32]

  hipMemsetAsync(zbase, 0, zbytes, stream);
  hipMemsetAsync(csr_src + E, 0, (size_t)4 * (Emax - E), stream);  // tail guard only

  // CSR build + weight pack: bucket hist/pack -> seg scan -> bucket scatter ->
  // final scatter (emits counts + rsp itself; no global count atomics anywhere)
  const int packTot = 144 * 64 + 272 * 128 + 80 * 128;   // 54272
  const int packBlocks = (packTot + 255) / 256;          // 212
  hist_pack_k<<<P2B + packBlocks, 256, 0, stream>>>(dst, bhist, E, NB, chunk, P2B,
                                                    W0, al0, ar0, W1, al1, ar1, resW1,
                                                    W2, al2, ar2, resW2, w0t, w1t, w2t);
  pscan1<<<nbB, 256, 0, stream>>>(bhist, bsumB, segN);
  pscan2<<<nbB, 256, 0, stream>>>(bhist, bsumB, segN, nbB);
  bscatter_k<<<P2B, 256, 0, stream>>>(src, dst, bhist, ebuf, E, NB, chunk);
  fscatter_k<<<NB, 256, 0, stream>>>(ebuf, bhist, csr_src, counts, rsp, E, NB, P2B, N);

  const int rowTiles = N / 16;                  // 6250, divisible by R=5
  const int rowGroups = rowTiles / 5;           // 1250
  const int aggblocks = (N + 3) / 4;            // wave per node

  // Layer 0 (A = x fp32, no colmean fold); CG=2 -> 2500 waves
  gemm_bf16<64, 144, 5, 2, 128, 4, 144, true, false><<<(rowGroups * 2 + 3) / 4, 256, 0, stream>>>(
      x, w0t, nullptr, feat8, el4, er4, nullptr, rowTiles);
  aggregate4<0><<<aggblocks, 256, 0, stream>>>(feat8, el4, er4, csr_src, rsp, counts, nullptr, vbf, rnrm, N);
  colsum_k<<<512, 256, 0, stream>>>(vbf, rnrm, colsumA, N);
  cmw_k<<<2, 256, 0, stream>>>(colsumA, w1t, cmw1, 128, 272, invN);

  // Layer 1 (A = vbf, colmean via cmw1); CG=4 -> 5000 waves
  gemm_bf16<128, 272, 5, 4, 128, 4, 144, false, true><<<rowGroups, 256, 0, stream>>>(
      vbf, w1t, cmw1, feat8, el4, er4, resh, rowTiles);
  aggregate4<1><<<aggblocks, 256, 0, stream>>>(feat8, el4, er4, csr_src, rsp, counts, resh, vbf, rnrm, N);
  colsum_k<<<512, 256, 0, stream>>>(vbf, rnrm, colsumB, N);
  cmw_k<<<1, 256, 0, stream>>>(colsumB, w2t, cmw2, 128, 80, invN);

  // Layer 2 (A = vbf, colmean via cmw2); CG=2 -> 2500 waves
  gemm_bf16<128, 80, 5, 2, 32, 1, 48, false, true><<<(rowGroups * 2 + 3) / 4, 256, 0, stream>>>(
      vbf, w2t, cmw2, feat8, el4, er4, resh, rowTiles);
  aggregate1<<<aggblocks, 256, 0, stream>>>(feat8, el4, er4, csr_src, rsp, counts, resh, out2, N);
  final_reduce<<<512, 256, 0, stream>>>(out2, outsum, N);
  finalize_k<<<1, 64, 0, stream>>>(outsum, (float*)d_out, invN);
}

// Round 8
// 488.842 us; speedup vs baseline: 1.2552x; 1.1306x over previous
//
#include <hip/hip_runtime.h>

// GAT 3-layer forward on MI355X — round 20.
// R19 post-mortem: gemm stuck at ~70us across R/CG variants; time tracks per-wave
// GLOBAL B-load count (R=1 -> 158us proves it); all pipes <10% busy -> B-load
// latency chain, unfixable by TLP alone. R20: canonical LDS-staged B —
//  - block = 4 waves x R=2 row-tiles (128 rows); B-tile (hi+lo, 8KB max) staged in
//    LDS once per block, ds_read_b128 (12cy) feeds MFMA.
//  - T14 split: next ct's B prefetched into regs during compute; ds_write after the
//    end-of-ct barrier; single LDS buffer, 2 barriers/ct.
//  - G4 swizzle: byte ^= ((row&7)<<4) on ds_write addr (reg-staged => free) and on
//    ds_read addr — kills the 16-way conflict of 256B-stride row reads.
// CSR pipeline + aggregates unchanged from R18/R19.

typedef __attribute__((ext_vector_type(8))) short s8v;
typedef __attribute__((ext_vector_type(4))) float f4v;
typedef __attribute__((ext_vector_type(2))) float f2v;
typedef __attribute__((ext_vector_type(2))) _Float16 h2;
typedef __attribute__((ext_vector_type(4))) _Float16 h4;

__device__ __forceinline__ unsigned short f2bf(float f) {
  unsigned int x = __float_as_uint(f);
  x += 0x7fffu + ((x >> 16) & 1u);          // RTNE
  return (unsigned short)(x >> 16);
}
__device__ __forceinline__ float bf2f(unsigned short u) {
  return __uint_as_float(((unsigned int)u) << 16);
}
__device__ __forceinline__ unsigned short f2h(float f) {
  _Float16 h = (_Float16)f;
  return __builtin_bit_cast(unsigned short, h);
}
__device__ __forceinline__ unsigned char f2fp8(float v) {
  return (unsigned char)(__builtin_amdgcn_cvt_pk_fp8_f32(v, v, 0, false) & 0xff);
}
__device__ __forceinline__ float lrelu(float x) { return fmaxf(x, 0.2f * x); }
__device__ __forceinline__ float elu1(float x) { return x > 0.f ? x : __expf(x) - 1.f; }

// ---------------- fused bucket histogram + weight pack (one launch) ----------------
__device__ __forceinline__ void pack_one(const float* W, const float* al, const float* ar,
                                         const float* resW, unsigned short* out,
                                         int K, int M, int BF, int H, int RES0, int t) {
  int c = t / K, k = t - c * K;
  float v = 0.f;
  if (c < BF) {
    v = W[k * BF + c];
  } else if (c < BF + H) {
    int h = c - BF;
    float s = 0.f;
    for (int d = 0; d < 32; d++) s += W[k * BF + h * 32 + d] * al[h * 32 + d];
    v = s;
  } else if (c < BF + 2 * H) {
    int h = c - BF - H;
    float s = 0.f;
    for (int d = 0; d < 32; d++) s += W[k * BF + h * 32 + d] * ar[h * 32 + d];
    v = s;
  } else if (c >= RES0) {
    v = resW[k * (M - RES0) + (c - RES0)];
  }
  unsigned short hi = f2bf(v);
  out[c * K + k] = hi;
  out[M * K + c * K + k] = f2bf(v - bf2f(hi));
}

__global__ __launch_bounds__(256) void hist_pack_k(const int* __restrict__ dst,
                                                   int* __restrict__ bhist, int E, int NB, int chunk, int P2B,
                                                   const float* __restrict__ W0, const float* __restrict__ al0,
                                                   const float* __restrict__ ar0,
                                                   const float* __restrict__ W1, const float* __restrict__ al1,
                                                   const float* __restrict__ ar1, const float* __restrict__ resW1,
                                                   const float* __restrict__ W2, const float* __restrict__ al2,
                                                   const float* __restrict__ ar2, const float* __restrict__ resW2,
                                                   unsigned short* __restrict__ w0t, unsigned short* __restrict__ w1t,
                                                   unsigned short* __restrict__ w2t) {
  if ((int)blockIdx.x < P2B) {
    __shared__ int h[512];
    for (int b = threadIdx.x; b < NB; b += 256) h[b] = 0;
    __syncthreads();
    int e0 = blockIdx.x * chunk;
    int e1 = min(E, e0 + chunk);
    for (int e = e0 + threadIdx.x; e < e1; e += 256) atomicAdd(&h[dst[e] >> 8], 1);
    __syncthreads();
    for (int b = threadIdx.x; b < NB; b += 256)
      bhist[(size_t)b * P2B + blockIdx.x] = h[b];
  } else {
    const int n0 = 144 * 64, n1 = 272 * 128, n2 = 80 * 128;
    int t = ((int)blockIdx.x - P2B) * 256 + threadIdx.x;
    if (t < n0) {
      pack_one(W0, al0, ar0, nullptr, w0t, 64, 144, 128, 4, 144, t);
    } else if (t < n0 + n1) {
      pack_one(W1, al1, ar1, resW1, w1t, 128, 272, 128, 4, 144, t - n0);
    } else if (t < n0 + n1 + n2) {
      pack_one(W2, al2, ar2, resW2, w2t, 128, 80, 32, 1, 48, t - n0 - n1);
    }
  }
}

// ---------------- bucket-segment table scan (two phases) ----------------
__global__ __launch_bounds__(256) void pscan1(int* __restrict__ arr, int* __restrict__ bsum, int Nn) {
  __shared__ int s[256];
  int t = threadIdx.x;
  int base = blockIdx.x * 1024 + t * 4;
  int v0 = (base + 0 < Nn) ? arr[base + 0] : 0;
  int v1 = (base + 1 < Nn) ? arr[base + 1] : 0;
  int v2 = (base + 2 < Nn) ? arr[base + 2] : 0;
  int v3 = (base + 3 < Nn) ? arr[base + 3] : 0;
  s[t] = v0 + v1 + v2 + v3;
  __syncthreads();
  for (int off = 1; off < 256; off <<= 1) {
    int xv = (t >= off) ? s[t - off] : 0;
    __syncthreads();
    s[t] += xv;
    __syncthreads();
  }
  int excl = t ? s[t - 1] : 0;
  if (t == 255) bsum[blockIdx.x] = s[255];
  if (base + 0 < Nn) { arr[base + 0] = excl; excl += v0; }
  if (base + 1 < Nn) { arr[base + 1] = excl; excl += v1; }
  if (base + 2 < Nn) { arr[base + 2] = excl; excl += v2; }
  if (base + 3 < Nn) { arr[base + 3] = excl; }
}

__global__ __launch_bounds__(256) void pscan2(int* __restrict__ arr, const int* __restrict__ bsum,
                                              int Nn, int nb) {
  __shared__ int s[256];
  int t = threadIdx.x;
  s[t] = (t < nb) ? bsum[t] : 0;
  __syncthreads();
  for (int off = 1; off < 256; off <<= 1) {
    int xv = (t >= off) ? s[t - off] : 0;
    __syncthreads();
    s[t] += xv;
    __syncthreads();
  }
  int bb = blockIdx.x;
  int pref = bb ? s[bb - 1] : 0;
  if (pref != 0) {
    int base = bb * 1024 + t * 4;
    if (base + 0 < Nn) arr[base + 0] += pref;
    if (base + 1 < Nn) arr[base + 1] += pref;
    if (base + 2 < Nn) arr[base + 2] += pref;
    if (base + 3 < Nn) arr[base + 3] += pref;
  }
}

// ---------------- pass 2: scatter edges into private (block,bucket) segments --------
__global__ __launch_bounds__(256) void bscatter_k(const int* __restrict__ src, const int* __restrict__ dst,
                                                  const int* __restrict__ seg, unsigned int* __restrict__ ebuf,
                                                  int E, int NB, int chunk) {
  __shared__ int cur[512];
  for (int b = threadIdx.x; b < NB; b += 256)
    cur[b] = seg[(size_t)b * gridDim.x + blockIdx.x];
  __syncthreads();
  int e0 = blockIdx.x * chunk;
  int e1 = min(E, e0 + chunk);
  for (int e = e0 + threadIdx.x; e < e1; e += 256) {
    int d = dst[e];
    int pos = atomicAdd(&cur[d >> 8], 1);
    ebuf[pos] = ((unsigned int)src[e] << 8) | (unsigned int)(d & 255);
  }
}

// ---------------- pass 3: per-bucket final scatter + counts/rsp emission ------------
__global__ __launch_bounds__(256) void fscatter_k(const unsigned int* __restrict__ ebuf,
                                                  const int* __restrict__ seg,
                                                  int* __restrict__ csr_src,
                                                  int* __restrict__ counts, int* __restrict__ rsp,
                                                  int E, int NB, int P2B, int Nn) {
  __shared__ int cnt[256];
  __shared__ int sc[256];
  __shared__ int cur[256];
  int b = blockIdx.x;
  int t = threadIdx.x;
  cnt[t] = 0;
  __syncthreads();
  int bstart = seg[(size_t)b * P2B];
  int bend = (b + 1 < NB) ? seg[(size_t)(b + 1) * P2B] : E;
  for (int e = bstart + t; e < bend; e += 256)
    atomicAdd(&cnt[ebuf[e] & 255u], 1);
  __syncthreads();
  int v = cnt[t];
  sc[t] = v;
  __syncthreads();
  for (int off = 1; off < 256; off <<= 1) {
    int xv = (t >= off) ? sc[t - off] : 0;
    __syncthreads();
    sc[t] += xv;
    __syncthreads();
  }
  int base = bstart + (t ? sc[t - 1] : 0);
  int node = (b << 8) + t;
  if (node < Nn) { counts[node] = v; rsp[node] = base; }
  cur[t] = base;
  __syncthreads();
  for (int e = bstart + t; e < bend; e += 256) {
    unsigned int sd = ebuf[e];
    int pos = atomicAdd(&cur[sd & 255u], 1);
    csr_src[pos] = (int)(sd >> 8);
  }
}

// ---------------- cmw[col] = invN * colsum @ (W_hi + W_lo)  (rank-1 PairNorm fold) ----
__global__ __launch_bounds__(256) void cmw_k(const float* __restrict__ colsum,
                                             const unsigned short* __restrict__ wt,
                                             float* __restrict__ cmw, int K, int M, float invN) {
  int c = blockIdx.x * 256 + threadIdx.x;
  if (c >= M) return;
  float s = 0.f;
  for (int k = 0; k < K; k++)
    s += colsum[k] * (bf2f(wt[c * K + k]) + bf2f(wt[(size_t)M * K + c * K + k]));
  cmw[c] = s * invN;
}

// ---------------- GEMM: A[N,K] @ Bt[M,K](bf16 hi+lo), LDS-staged B ----------------
// Block = 4 waves x R row-tiles. Per ct: B-tile (hi+lo) in LDS (swizzled), all waves
// ds_read + MFMA; next ct's B prefetched into regs during compute (T14).
template <int K, int M, int R, int BF, int H, int RES0, bool AF32, bool CMW>
__global__ __launch_bounds__(256) void gemm_bf16(const void* __restrict__ Av,
                                                 const unsigned short* __restrict__ Bt,
                                                 const float* __restrict__ cmw,
                                                 unsigned char* __restrict__ feat8,
                                                 float* __restrict__ el, float* __restrict__ er,
                                                 unsigned short* __restrict__ resh, int nRowTiles) {
  constexpr int NT = M / 16;              // column tiles
  constexpr int PLANE = 16 * K * 2;       // bytes per B plane (4096 or 2048)
  constexpr int RS = (K == 128) ? 8 : 7;  // log2(row bytes) for swizzle
  __shared__ unsigned char bbuf[2 * PLANE];  // [hi | lo]
  int t = threadIdx.x;
  int w = t >> 6;
  int lane = t & 63;
  int tile0 = (int)blockIdx.x * (4 * R) + w * R;
  int r = lane & 15, q = lane >> 4;

  // ---- A fragments (guarded per tile; invalid waves still barrier-loop) ----
  s8v afrag[R][K / 32];
  bool valid[R];
#pragma unroll
  for (int rr = 0; rr < R; rr++) {
    valid[rr] = (tile0 + rr) < nRowTiles;
    if (valid[rr]) {
      if constexpr (AF32) {
        const float* arow = (const float*)Av + (size_t)((tile0 + rr) * 16 + r) * K + q * 8;
#pragma unroll
        for (int kk = 0; kk < K / 32; kk++) {
          s8v v;
#pragma unroll
          for (int j = 0; j < 8; j++) v[j] = (short)f2bf(arow[kk * 32 + j]);
          afrag[rr][kk] = v;
        }
      } else {
        const unsigned short* arow = (const unsigned short*)Av + (size_t)((tile0 + rr) * 16 + r) * K + q * 8;
#pragma unroll
        for (int kk = 0; kk < K / 32; kk++) afrag[rr][kk] = *(const s8v*)(arow + kk * 32);
      }
    }
  }

  const unsigned char* gBhi = (const unsigned char*)Bt;
  const unsigned char* gBlo = (const unsigned char*)Bt + (size_t)M * K * 2;

  // ---- B stage prologue: load ct=0 into regs ----
  uint4 rh = {0, 0, 0, 0}, rl = {0, 0, 0, 0};
  if constexpr (K == 128) {
    rh = *(const uint4*)(gBhi + (size_t)0 * PLANE + t * 16);
    rl = *(const uint4*)(gBlo + (size_t)0 * PLANE + t * 16);
  } else {
    if (t < 128) rh = *(const uint4*)(gBhi + t * 16);
    else         rl = *(const uint4*)(gBlo + (t - 128) * 16);
  }

  for (int ct = 0; ct < NT; ct++) {
    // write staged regs to LDS (swizzled: byte ^= ((row&7)<<4))
    if constexpr (K == 128) {
      unsigned x = (unsigned)t * 16;
      unsigned d = x ^ (((x >> RS) & 7u) << 4);
      *(uint4*)(bbuf + d) = rh;
      *(uint4*)(bbuf + PLANE + d) = rl;
    } else {
      if (t < 128) {
        unsigned x = (unsigned)t * 16;
        unsigned d = x ^ (((x >> RS) & 7u) << 4);
        *(uint4*)(bbuf + d) = rh;
      } else {
        unsigned x = (unsigned)(t - 128) * 16;
        unsigned d = x ^ (((x >> RS) & 7u) << 4);
        *(uint4*)(bbuf + PLANE + d) = rl;
      }
    }
    __syncthreads();
    // prefetch next ct's B into regs — hides global latency under compute
    if (ct + 1 < NT) {
      if constexpr (K == 128) {
        rh = *(const uint4*)(gBhi + (size_t)(ct + 1) * PLANE + t * 16);
        rl = *(const uint4*)(gBlo + (size_t)(ct + 1) * PLANE + t * 16);
      } else {
        if (t < 128) rh = *(const uint4*)(gBhi + (size_t)(ct + 1) * PLANE + t * 16);
        else         rl = *(const uint4*)(gBlo + (size_t)(ct + 1) * PLANE + (t - 128) * 16);
      }
    }
    // read B fragments from LDS (swizzled)
    s8v bhi[K / 32], blo[K / 32];
#pragma unroll
    for (int kk = 0; kk < K / 32; kk++) {
      unsigned off = (unsigned)(q * 16 + kk * 64);
      unsigned ad = ((unsigned)r << RS) + (off ^ (((unsigned)(r & 7)) << 4));
      bhi[kk] = *(const s8v*)(bbuf + ad);
      blo[kk] = *(const s8v*)(bbuf + PLANE + ad);
    }
    int col = ct * 16 + r;
    float cmwv = 0.f;
    if constexpr (CMW) cmwv = cmw[col];
#pragma unroll
    for (int rr = 0; rr < R; rr++) {
      if (!valid[rr]) continue;
      f4v acc = {0.f, 0.f, 0.f, 0.f};
#pragma unroll
      for (int kk = 0; kk < K / 32; kk++) {
        acc = __builtin_amdgcn_mfma_f32_16x16x32_bf16(afrag[rr][kk], bhi[kk], acc, 0, 0, 0);
        acc = __builtin_amdgcn_mfma_f32_16x16x32_bf16(afrag[rr][kk], blo[kk], acc, 0, 0, 0);
      }
      int row0 = (tile0 + rr) * 16 + q * 4;
#pragma unroll
      for (int i = 0; i < 4; i++) {
        float v = acc[i] - cmwv;
        size_t row = (size_t)(row0 + i);
        if (col < BF) {
          feat8[row * BF + col] = f2fp8(v);
        } else if (col < BF + H) {
          el[row * H + (col - BF)] = v;
        } else if (col < BF + 2 * H) {
          er[row * H + (col - BF - H)] = v;
        } else if (RES0 < M && col >= RES0) {
          resh[row * (M - RES0) + (col - RES0)] = f2h(v);
        }
      }
    }
    __syncthreads();   // all reads of bbuf done before next ct's ds_write
  }
}

// ---------------- fused single-pass aggregation H=4 (fp8 feat table) ----------------
template <int MODE>
__global__ __launch_bounds__(256) void aggregate4(const unsigned char* __restrict__ feat8,
                                                  const float* __restrict__ el4,
                                                  const float* __restrict__ er4,
                                                  const int* __restrict__ csr_src,
                                                  const int* __restrict__ rsp,
                                                  const int* __restrict__ counts,
                                                  const unsigned short* __restrict__ resh,
                                                  unsigned short* __restrict__ vbf,
                                                  float* __restrict__ rnrm, int Nn) {
  int n = (int)((blockIdx.x * blockDim.x + threadIdx.x) >> 6);
  if (n >= Nn) return;
  int lane = threadIdx.x & 63;
  int start = __builtin_amdgcn_readfirstlane(rsp[n]);
  int deg = __builtin_amdgcn_readfirstlane(counts[n]);
  int chunks = (deg + 15) >> 4;
  int slot = lane >> 2, h = lane & 3;
  float ern = er4[(size_t)n * 4 + h];
  int hl = lane >> 4;                        // head of lane's dims (dims 2l..2l+1)
  unsigned dby = (unsigned)lane << 1;        // byte offset into 128B fp8 row
  f2v a01 = {0.f, 0.f};
  float dsum = 0.f;
  // prologue: chunk 0's phase-A gather
  float elv = el4[(size_t)csr_src[start + slot] * 4 + h];
  for (int c = 0; c < chunks; c++) {
    const int* csp = csr_src + start + (c << 4);
    int sj[16];
#pragma unroll
    for (int j = 0; j < 16; j++) sj[j] = csp[j];
    float e = elv + ern;
    float exv = (((c << 4) + slot) < deg) ? __expf(fmaxf(e, 0.2f * e)) : 0.f;
    dsum += exv;
    if (c + 1 < chunks) elv = el4[(size_t)csp[16 + slot] * 4 + h];
#pragma unroll
    for (int j = 0; j < 16; j++) {
      float aw = __shfl(exv, (j << 2) | hl);
      unsigned short u = *(const unsigned short*)(feat8 + (((unsigned)sj[j] << 7) + dby));
      f2v fv = __builtin_amdgcn_cvt_pk_f32_fp8((int)u, false);
      f2v aw2 = {aw, aw};
      a01 = __builtin_elementwise_fma(fv, aw2, a01);
    }
  }
#pragma unroll
  for (int off = 4; off < 64; off <<= 1) dsum += __shfl_xor(dsum, off);
  float inv = dsum > 0.f ? 1.f / dsum : 0.f;
  float invh = __shfl(inv, hl);
  float v0, v1;
  if (MODE == 1) {
    h2 rr = *(const h2*)(resh + (size_t)n * 128 + lane * 2);
    v0 = elu1(elu1(a01[0] * invh + (float)rr[0]));
    v1 = elu1(elu1(a01[1] * invh + (float)rr[1]));
  } else {
    v0 = elu1(a01[0] * invh);
    v1 = elu1(a01[1] * invh);
  }
  float ss = v0 * v0 + v1 * v1;
#pragma unroll
  for (int off = 1; off < 64; off <<= 1) ss += __shfl_xor(ss, off);
  float rn = sqrtf(1e-6f + ss);
  float ri = 1.f / rn;
  unsigned int pk = (unsigned int)f2bf(v0 * ri) | ((unsigned int)f2bf(v1 * ri) << 16);
  *(unsigned int*)((char*)vbf + ((size_t)n << 8) + (lane << 2)) = pk;
  if (lane == 0) rnrm[n] = rn;
}

// ---------------- fused single-pass aggregation H=1 (layer 2, fp8 table) ----------------
__global__ __launch_bounds__(256) void aggregate1(const unsigned char* __restrict__ feat8,
                                                  const float* __restrict__ el1,
                                                  const float* __restrict__ er1,
                                                  const int* __restrict__ csr_src,
                                                  const int* __restrict__ rsp,
                                                  const int* __restrict__ counts,
                                                  const unsigned short* __restrict__ res2h,
                                                  float* __restrict__ out2, int Nn) {
  int n = (int)((blockIdx.x * blockDim.x + threadIdx.x) >> 6);
  if (n >= Nn) return;
  int lane = threadIdx.x & 63;
  int start = __builtin_amdgcn_readfirstlane(rsp[n]);
  int deg = __builtin_amdgcn_readfirstlane(counts[n]);
  int chunks = (deg + 15) >> 4;
  int l16 = lane & 15;
  float ern = er1[n];
  int g = lane >> 3;                          // 8 edge groups (2 edges each per chunk)
  unsigned dofs4 = (unsigned)(lane & 7) << 2; // byte offset into 32B fp8 row
  f2v acc01 = {0.f, 0.f}, acc23 = {0.f, 0.f};
  float dsum = 0.f;
  int sA = csr_src[start + l16];
  float elv = el1[sA];
  for (int c = 0; c < chunks; c++) {
    const int* csp = csr_src + start + (c << 4);
    float exv = (((c << 4) + l16) < deg) ? __expf(lrelu(elv + ern)) : 0.f;
    dsum += exv;
    int sAc = sA;
    if (c + 1 < chunks) {
      sA = csp[16 + l16];
      elv = el1[sA];
    }
#pragma unroll
    for (int t = 0; t < 2; t++) {
      int j = (t << 3) + g;
      int sj = __shfl(sAc, j);
      float aw = __shfl(exv, j);
      f2v aw2 = {aw, aw};
      unsigned int u = *(const unsigned int*)(feat8 + (((unsigned)sj << 5) + dofs4));
      f2v fa = __builtin_amdgcn_cvt_pk_f32_fp8((int)u, false);
      f2v fb = __builtin_amdgcn_cvt_pk_f32_fp8((int)u, true);
      acc01 = __builtin_elementwise_fma(fa, aw2, acc01);
      acc23 = __builtin_elementwise_fma(fb, aw2, acc23);
    }
  }
#pragma unroll
  for (int off = 1; off < 16; off <<= 1) dsum += __shfl_xor(dsum, off);
  float inv = dsum > 0.f ? 1.f / dsum : 0.f;
#pragma unroll
  for (int off = 8; off < 64; off <<= 1) {
    acc01[0] += __shfl_xor(acc01[0], off);
    acc01[1] += __shfl_xor(acc01[1], off);
    acc23[0] += __shfl_xor(acc23[0], off);
    acc23[1] += __shfl_xor(acc23[1], off);
  }
  if (lane < 8) {
    h4 rr = *(const h4*)(res2h + (size_t)n * 32 + (lane << 2));
    float4 o;
    o.x = acc01[0] * inv + (float)rr[0];
    o.y = acc01[1] * inv + (float)rr[1];
    o.z = acc23[0] * inv + (float)rr[2];
    o.w = acc23[1] * inv + (float)rr[3];
    *(float4*)(out2 + (size_t)n * 32 + (lane << 2)) = o;
  }
}

// ---------------- colsum of raw v = vbf * rnrm (PairNorm colmean numerator) ----------------
__global__ __launch_bounds__(256) void colsum_k(const unsigned short* __restrict__ vbf,
                                                const float* __restrict__ rnrm,
                                                float* __restrict__ colsum, int Nn) {
  __shared__ float ls[256];
  int tid = threadIdx.x;
  int c = tid & 127, rsub = tid >> 7;
  float cs = 0.f;
  for (int r = blockIdx.x * 2 + rsub; r < Nn; r += gridDim.x * 2)
    cs += bf2f(vbf[(size_t)r * 128 + c]) * rnrm[r];
  ls[tid] = cs;
  __syncthreads();
  if (tid < 128) atomicAdd(&colsum[tid], ls[tid] + ls[tid + 128]);
}

// ---------------- final: mean over nodes of out2 ----------------
__global__ __launch_bounds__(256) void final_reduce(const float* __restrict__ out2,
                                                    float* __restrict__ outsum, int Nn) {
  __shared__ float ls[32];
  if (threadIdx.x < 32) ls[threadIdx.x] = 0.f;
  __syncthreads();
  int d = threadIdx.x & 31, rl = threadIdx.x >> 5;
  float acc = 0.f;
  for (int n = blockIdx.x * 8 + rl; n < Nn; n += gridDim.x * 8)
    acc += out2[(size_t)n * 32 + d];
  atomicAdd(&ls[d], acc);
  __syncthreads();
  if (threadIdx.x < 32) atomicAdd(&outsum[threadIdx.x], ls[threadIdx.x]);
}

__global__ void finalize_k(const float* __restrict__ outsum, float* __restrict__ out, float invN) {
  int t = threadIdx.x;
  if (t < 32) out[t] = outsum[t] * invN;
}

// ---------------- launcher ----------------
extern "C" void kernel_launch(void* const* d_in, const int* in_sizes, int n_in,
                              void* d_out, int out_size, void* d_ws, size_t ws_size,
                              hipStream_t stream) {
  const float* x     = (const float*)d_in[0];
  const int*   src   = (const int*)d_in[1];
  const int*   dst   = (const int*)d_in[2];
  const float* W0    = (const float*)d_in[3];
  const float* al0   = (const float*)d_in[4];
  const float* ar0   = (const float*)d_in[5];
  const float* W1    = (const float*)d_in[6];
  const float* al1   = (const float*)d_in[7];
  const float* ar1   = (const float*)d_in[8];
  const float* resW1 = (const float*)d_in[9];
  const float* W2    = (const float*)d_in[10];
  const float* al2   = (const float*)d_in[11];
  const float* ar2   = (const float*)d_in[12];
  const float* resW2 = (const float*)d_in[13];
  const int N = in_sizes[0] / 64;   // 100000
  const int E = in_sizes[1];        // 1600000
  const float invN = 1.f / (float)N;
  const int Emax = E + 64;              // unpadded CSR + zeroed tail guard
  const int NB = (N + 255) >> 8;        // dst buckets of 256 nodes (391)
  const int P2B = 512;                  // histogram/scatter block count
  const int chunk = (E + P2B - 1) / P2B;
  const int segN = NB * P2B;            // bucket-major segment table length
  const int nbB = (segN + 1023) / 1024; // scan blocks for segment table (196)

  char* p = (char*)d_ws;
  auto alloc = [&](size_t bytes) { char* r = p; p += (bytes + 255) & ~(size_t)255; return r; };

  // zero-initialized region (small: reduction accumulators only)
  char* zbase = p;
  float* colsumA = (float*)alloc(512);
  float* colsumB = (float*)alloc(512);
  float* outsum  = (float*)alloc(128);
  size_t zbytes = (size_t)(p - zbase);

  int* counts = (int*)alloc((size_t)4 * N);     // written by fscatter
  int* rsp    = (int*)alloc((size_t)4 * N);     // written by fscatter (unpadded row starts)
  int* bsumB  = (int*)alloc(1024);
  int* bhist  = (int*)alloc((size_t)4 * segN);  // per-(bucket,block) counts -> seg (scanned in place)
  unsigned int* ebuf = (unsigned int*)alloc((size_t)4 * E);  // packed (src<<8)|(dst&255)
  int* csr_src = (int*)alloc((size_t)4 * Emax);
  unsigned char*  feat8 = (unsigned char*)alloc((size_t)N * 128);     // fp8 gather table
  unsigned short* vbf   = (unsigned short*)alloc((size_t)2 * N * 128);
  unsigned short* resh  = (unsigned short*)alloc((size_t)2 * N * 128);  // f16 residuals
  unsigned short* w0t = (unsigned short*)alloc((size_t)2 * 2 * 144 * 64);
  unsigned short* w1t = (unsigned short*)alloc((size_t)2 * 2 * 272 * 128);
  unsigned short* w2t = (unsigned short*)alloc((size_t)2 * 2 * 80 * 128);
  float* el4  = (float*)alloc((size_t)16 * N);
  float* er4  = (float*)alloc((size_t)16 * N);
  float* rnrm = (float*)alloc((size_t)4 * N);
  float* cmw1 = (float*)alloc(4 * 272);
  float* cmw2 = (float*)alloc(4 * 80);
  float* out2 = (float*)alloc((size_t)4 * N * 32);   // layer-2 output [N][32]

  hipMemsetAsync(zbase, 0, zbytes, stream);
  hipMemsetAsync(csr_src + E, 0, (size_t)4 * (Emax - E), stream);  // tail guard only

  // CSR build + weight pack
  const int packTot = 144 * 64 + 272 * 128 + 80 * 128;   // 54272
  const int packBlocks = (packTot + 255) / 256;          // 212
  hist_pack_k<<<P2B + packBlocks, 256, 0, stream>>>(dst, bhist, E, NB, chunk, P2B,
                                                    W0, al0, ar0, W1, al1, ar1, resW1,
                                                    W2, al2, ar2, resW2, w0t, w1t, w2t);
  pscan1<<<nbB, 256, 0, stream>>>(bhist, bsumB, segN);
  pscan2<<<nbB, 256, 0, stream>>>(bhist, bsumB, segN, nbB);
  bscatter_k<<<P2B, 256, 0, stream>>>(src, dst, bhist, ebuf, E, NB, chunk);
  fscatter_k<<<NB, 256, 0, stream>>>(ebuf, bhist, csr_src, counts, rsp, E, NB, P2B, N);

  const int rowTiles = N / 16;                   // 6250
  const int gblocks = (rowTiles + 7) / 8;        // 4 waves x R=2 tiles = 8 tiles/block
  const int aggblocks = (N + 3) / 4;             // wave per node

  // Layer 0 (A = x fp32, no colmean fold)
  gemm_bf16<64, 144, 2, 128, 4, 144, true, false><<<gblocks, 256, 0, stream>>>(
      x, w0t, nullptr, feat8, el4, er4, nullptr, rowTiles);
  aggregate4<0><<<aggblocks, 256, 0, stream>>>(feat8, el4, er4, csr_src, rsp, counts, nullptr, vbf, rnrm, N);
  colsum_k<<<512, 256, 0, stream>>>(vbf, rnrm, colsumA, N);
  cmw_k<<<2, 256, 0, stream>>>(colsumA, w1t, cmw1, 128, 272, invN);

  // Layer 1 (A = vbf, colmean via cmw1)
  gemm_bf16<128, 272, 2, 128, 4, 144, false, true><<<gblocks, 256, 0, stream>>>(
      vbf, w1t, cmw1, feat8, el4, er4, resh, rowTiles);
  aggregate4<1><<<aggblocks, 256, 0, stream>>>(feat8, el4, er4, csr_src, rsp, counts, resh, vbf, rnrm, N);
  colsum_k<<<512, 256, 0, stream>>>(vbf, rnrm, colsumB, N);
  cmw_k<<<1, 256, 0, stream>>>(colsumB, w2t, cmw2, 128, 80, invN);

  // Layer 2 (A = vbf, colmean via cmw2)
  gemm_bf16<128, 80, 2, 32, 1, 48, false, true><<<gblocks, 256, 0, stream>>>(
      vbf, w2t, cmw2, feat8, el4, er4, resh, rowTiles);
  aggregate1<<<aggblocks, 256, 0, stream>>>(feat8, el4, er4, csr_src, rsp, counts, resh, out2, N);
  final_reduce<<<512, 256, 0, stream>>>(out2, outsum, N);
  finalize_k<<<1, 64, 0, stream>>>(outsum, (float*)d_out, invN);
}

// Round 9
// 476.555 us; speedup vs baseline: 1.2876x; 1.0258x over previous
//
#include <hip/hip_runtime.h>

// GAT 3-layer forward on MI355X — round 21.
// R20 landed (552.7 -> 488.8): LDS-staged-B gemm out of top-5. aggregate4 now leads
// (62.5us x2), at ~2.8 TB/s random-gather from L3 (FETCH 143.5MB vs 12.8MB table:
// L2 holds ~30%). Changes:
//  - aggregate4: prefetch next chunk's sj batch (s_loads) during FMA phase —
//    removes the one remaining serial SMEM round-trip per chunk.
//  - pscan2 removed: bscatter/fscatter re-derive block-sum prefixes locally
//    (196-entry LDS scan of bsumB).
//  - int4-vectorized edge reads in hist_pack/bscatter (chunk rounded to x4);
//    packed-uint colsum.

typedef __attribute__((ext_vector_type(8))) short s8v;
typedef __attribute__((ext_vector_type(4))) float f4v;
typedef __attribute__((ext_vector_type(2))) float f2v;
typedef __attribute__((ext_vector_type(2))) _Float16 h2;
typedef __attribute__((ext_vector_type(4))) _Float16 h4;

__device__ __forceinline__ unsigned short f2bf(float f) {
  unsigned int x = __float_as_uint(f);
  x += 0x7fffu + ((x >> 16) & 1u);          // RTNE
  return (unsigned short)(x >> 16);
}
__device__ __forceinline__ float bf2f(unsigned short u) {
  return __uint_as_float(((unsigned int)u) << 16);
}
__device__ __forceinline__ unsigned short f2h(float f) {
  _Float16 h = (_Float16)f;
  return __builtin_bit_cast(unsigned short, h);
}
__device__ __forceinline__ unsigned char f2fp8(float v) {
  return (unsigned char)(__builtin_amdgcn_cvt_pk_fp8_f32(v, v, 0, false) & 0xff);
}
__device__ __forceinline__ float lrelu(float x) { return fmaxf(x, 0.2f * x); }
__device__ __forceinline__ float elu1(float x) { return x > 0.f ? x : __expf(x) - 1.f; }

// ---------------- fused bucket histogram + weight pack (one launch) ----------------
__device__ __forceinline__ void pack_one(const float* W, const float* al, const float* ar,
                                         const float* resW, unsigned short* out,
                                         int K, int M, int BF, int H, int RES0, int t) {
  int c = t / K, k = t - c * K;
  float v = 0.f;
  if (c < BF) {
    v = W[k * BF + c];
  } else if (c < BF + H) {
    int h = c - BF;
    float s = 0.f;
    for (int d = 0; d < 32; d++) s += W[k * BF + h * 32 + d] * al[h * 32 + d];
    v = s;
  } else if (c < BF + 2 * H) {
    int h = c - BF - H;
    float s = 0.f;
    for (int d = 0; d < 32; d++) s += W[k * BF + h * 32 + d] * ar[h * 32 + d];
    v = s;
  } else if (c >= RES0) {
    v = resW[k * (M - RES0) + (c - RES0)];
  }
  unsigned short hi = f2bf(v);
  out[c * K + k] = hi;
  out[M * K + c * K + k] = f2bf(v - bf2f(hi));
}

__global__ __launch_bounds__(256) void hist_pack_k(const int* __restrict__ dst,
                                                   int* __restrict__ bhist, int E, int NB, int chunk, int P2B,
                                                   const float* __restrict__ W0, const float* __restrict__ al0,
                                                   const float* __restrict__ ar0,
                                                   const float* __restrict__ W1, const float* __restrict__ al1,
                                                   const float* __restrict__ ar1, const float* __restrict__ resW1,
                                                   const float* __restrict__ W2, const float* __restrict__ al2,
                                                   const float* __restrict__ ar2, const float* __restrict__ resW2,
                                                   unsigned short* __restrict__ w0t, unsigned short* __restrict__ w1t,
                                                   unsigned short* __restrict__ w2t) {
  if ((int)blockIdx.x < P2B) {
    __shared__ int h[512];
    for (int b = threadIdx.x; b < NB; b += 256) h[b] = 0;
    __syncthreads();
    int e0 = blockIdx.x * chunk;
    int e1 = min(E, e0 + chunk);
    int e = e0 + threadIdx.x * 4;
    for (; e + 3 < e1; e += 1024) {
      int4 d4 = *(const int4*)(dst + e);
      atomicAdd(&h[d4.x >> 8], 1);
      atomicAdd(&h[d4.y >> 8], 1);
      atomicAdd(&h[d4.z >> 8], 1);
      atomicAdd(&h[d4.w >> 8], 1);
    }
    for (; e < e1; e++) atomicAdd(&h[dst[e] >> 8], 1);
    __syncthreads();
    for (int b = threadIdx.x; b < NB; b += 256)
      bhist[(size_t)b * P2B + blockIdx.x] = h[b];
  } else {
    const int n0 = 144 * 64, n1 = 272 * 128, n2 = 80 * 128;
    int t = ((int)blockIdx.x - P2B) * 256 + threadIdx.x;
    if (t < n0) {
      pack_one(W0, al0, ar0, nullptr, w0t, 64, 144, 128, 4, 144, t);
    } else if (t < n0 + n1) {
      pack_one(W1, al1, ar1, resW1, w1t, 128, 272, 128, 4, 144, t - n0);
    } else if (t < n0 + n1 + n2) {
      pack_one(W2, al2, ar2, resW2, w2t, 128, 80, 32, 1, 48, t - n0 - n1);
    }
  }
}

// ---------------- bucket-segment table scan (phase 1 only; prefix re-derived later) --
__global__ __launch_bounds__(256) void pscan1(int* __restrict__ arr, int* __restrict__ bsum, int Nn) {
  __shared__ int s[256];
  int t = threadIdx.x;
  int base = blockIdx.x * 1024 + t * 4;
  int v0 = (base + 0 < Nn) ? arr[base + 0] : 0;
  int v1 = (base + 1 < Nn) ? arr[base + 1] : 0;
  int v2 = (base + 2 < Nn) ? arr[base + 2] : 0;
  int v3 = (base + 3 < Nn) ? arr[base + 3] : 0;
  s[t] = v0 + v1 + v2 + v3;
  __syncthreads();
  for (int off = 1; off < 256; off <<= 1) {
    int xv = (t >= off) ? s[t - off] : 0;
    __syncthreads();
    s[t] += xv;
    __syncthreads();
  }
  int excl = t ? s[t - 1] : 0;
  if (t == 255) bsum[blockIdx.x] = s[255];
  if (base + 0 < Nn) { arr[base + 0] = excl; excl += v0; }
  if (base + 1 < Nn) { arr[base + 1] = excl; excl += v1; }
  if (base + 2 < Nn) { arr[base + 2] = excl; excl += v2; }
  if (base + 3 < Nn) { arr[base + 3] = excl; }
}

// ---------------- pass 2: scatter edges into private (block,bucket) segments --------
// seg prefix re-derived locally: LDS scan of bsumB (nbB <= 256 entries).
__global__ __launch_bounds__(256) void bscatter_k(const int* __restrict__ src, const int* __restrict__ dst,
                                                  const int* __restrict__ bhist, const int* __restrict__ bsumB,
                                                  unsigned int* __restrict__ ebuf,
                                                  int E, int NB, int chunk, int nbB) {
  __shared__ int pref[256];
  __shared__ int cur[512];
  int t = threadIdx.x;
  pref[t] = (t < nbB) ? bsumB[t] : 0;
  __syncthreads();
  for (int off = 1; off < 256; off <<= 1) {
    int xv = (t >= off) ? pref[t - off] : 0;
    __syncthreads();
    pref[t] += xv;
    __syncthreads();
  }
  for (int b = t; b < NB; b += 256) {
    size_t idx = (size_t)b * gridDim.x + blockIdx.x;
    int sb = (int)(idx >> 10);
    cur[b] = bhist[idx] + (sb ? pref[sb - 1] : 0);
  }
  __syncthreads();
  int e0 = blockIdx.x * chunk;
  int e1 = min(E, e0 + chunk);
  int e = e0 + t * 4;
  for (; e + 3 < e1; e += 1024) {
    int4 d4 = *(const int4*)(dst + e);
    int4 s4 = *(const int4*)(src + e);
    int p0 = atomicAdd(&cur[d4.x >> 8], 1);
    ebuf[p0] = ((unsigned int)s4.x << 8) | (unsigned int)(d4.x & 255);
    int p1 = atomicAdd(&cur[d4.y >> 8], 1);
    ebuf[p1] = ((unsigned int)s4.y << 8) | (unsigned int)(d4.y & 255);
    int p2 = atomicAdd(&cur[d4.z >> 8], 1);
    ebuf[p2] = ((unsigned int)s4.z << 8) | (unsigned int)(d4.z & 255);
    int p3 = atomicAdd(&cur[d4.w >> 8], 1);
    ebuf[p3] = ((unsigned int)s4.w << 8) | (unsigned int)(d4.w & 255);
  }
  for (; e < e1; e++) {
    int d = dst[e];
    int pos = atomicAdd(&cur[d >> 8], 1);
    ebuf[pos] = ((unsigned int)src[e] << 8) | (unsigned int)(d & 255);
  }
}

// ---------------- pass 3: per-bucket final scatter + counts/rsp emission ------------
__global__ __launch_bounds__(256) void fscatter_k(const unsigned int* __restrict__ ebuf,
                                                  const int* __restrict__ bhist, const int* __restrict__ bsumB,
                                                  int* __restrict__ csr_src,
                                                  int* __restrict__ counts, int* __restrict__ rsp,
                                                  int E, int NB, int P2B, int Nn, int nbB) {
  __shared__ int pref[256];
  __shared__ int cnt[256];
  __shared__ int sc[256];
  __shared__ int cur[256];
  int b = blockIdx.x;
  int t = threadIdx.x;
  pref[t] = (t < nbB) ? bsumB[t] : 0;
  cnt[t] = 0;
  __syncthreads();
  for (int off = 1; off < 256; off <<= 1) {
    int xv = (t >= off) ? pref[t - off] : 0;
    __syncthreads();
    pref[t] += xv;
    __syncthreads();
  }
  size_t i1 = (size_t)b * P2B;
  int sb1 = (int)(i1 >> 10);
  int bstart = bhist[i1] + (sb1 ? pref[sb1 - 1] : 0);
  int bend = E;
  if (b + 1 < NB) {
    size_t i2 = (size_t)(b + 1) * P2B;
    int sb2 = (int)(i2 >> 10);
    bend = bhist[i2] + (sb2 ? pref[sb2 - 1] : 0);
  }
  for (int e = bstart + t; e < bend; e += 256)
    atomicAdd(&cnt[ebuf[e] & 255u], 1);
  __syncthreads();
  int v = cnt[t];
  sc[t] = v;
  __syncthreads();
  for (int off = 1; off < 256; off <<= 1) {
    int xv = (t >= off) ? sc[t - off] : 0;
    __syncthreads();
    sc[t] += xv;
    __syncthreads();
  }
  int base = bstart + (t ? sc[t - 1] : 0);
  int node = (b << 8) + t;
  if (node < Nn) { counts[node] = v; rsp[node] = base; }
  cur[t] = base;
  __syncthreads();
  for (int e = bstart + t; e < bend; e += 256) {
    unsigned int sd = ebuf[e];
    int pos = atomicAdd(&cur[sd & 255u], 1);
    csr_src[pos] = (int)(sd >> 8);
  }
}

// ---------------- cmw[col] = invN * colsum @ (W_hi + W_lo)  (rank-1 PairNorm fold) ----
__global__ __launch_bounds__(256) void cmw_k(const float* __restrict__ colsum,
                                             const unsigned short* __restrict__ wt,
                                             float* __restrict__ cmw, int K, int M, float invN) {
  int c = blockIdx.x * 256 + threadIdx.x;
  if (c >= M) return;
  float s = 0.f;
  for (int k = 0; k < K; k++)
    s += colsum[k] * (bf2f(wt[c * K + k]) + bf2f(wt[(size_t)M * K + c * K + k]));
  cmw[c] = s * invN;
}

// ---------------- GEMM: A[N,K] @ Bt[M,K](bf16 hi+lo), LDS-staged B ----------------
template <int K, int M, int R, int BF, int H, int RES0, bool AF32, bool CMW>
__global__ __launch_bounds__(256) void gemm_bf16(const void* __restrict__ Av,
                                                 const unsigned short* __restrict__ Bt,
                                                 const float* __restrict__ cmw,
                                                 unsigned char* __restrict__ feat8,
                                                 float* __restrict__ el, float* __restrict__ er,
                                                 unsigned short* __restrict__ resh, int nRowTiles) {
  constexpr int NT = M / 16;              // column tiles
  constexpr int PLANE = 16 * K * 2;       // bytes per B plane (4096 or 2048)
  constexpr int RS = (K == 128) ? 8 : 7;  // log2(row bytes) for swizzle
  __shared__ unsigned char bbuf[2 * PLANE];  // [hi | lo]
  int t = threadIdx.x;
  int w = t >> 6;
  int lane = t & 63;
  int tile0 = (int)blockIdx.x * (4 * R) + w * R;
  int r = lane & 15, q = lane >> 4;

  // ---- A fragments (guarded per tile; invalid waves still barrier-loop) ----
  s8v afrag[R][K / 32];
  bool valid[R];
#pragma unroll
  for (int rr = 0; rr < R; rr++) {
    valid[rr] = (tile0 + rr) < nRowTiles;
    if (valid[rr]) {
      if constexpr (AF32) {
        const float* arow = (const float*)Av + (size_t)((tile0 + rr) * 16 + r) * K + q * 8;
#pragma unroll
        for (int kk = 0; kk < K / 32; kk++) {
          s8v v;
#pragma unroll
          for (int j = 0; j < 8; j++) v[j] = (short)f2bf(arow[kk * 32 + j]);
          afrag[rr][kk] = v;
        }
      } else {
        const unsigned short* arow = (const unsigned short*)Av + (size_t)((tile0 + rr) * 16 + r) * K + q * 8;
#pragma unroll
        for (int kk = 0; kk < K / 32; kk++) afrag[rr][kk] = *(const s8v*)(arow + kk * 32);
      }
    }
  }

  const unsigned char* gBhi = (const unsigned char*)Bt;
  const unsigned char* gBlo = (const unsigned char*)Bt + (size_t)M * K * 2;

  // ---- B stage prologue: load ct=0 into regs ----
  uint4 rh = {0, 0, 0, 0}, rl = {0, 0, 0, 0};
  if constexpr (K == 128) {
    rh = *(const uint4*)(gBhi + (size_t)0 * PLANE + t * 16);
    rl = *(const uint4*)(gBlo + (size_t)0 * PLANE + t * 16);
  } else {
    if (t < 128) rh = *(const uint4*)(gBhi + t * 16);
    else         rl = *(const uint4*)(gBlo + (t - 128) * 16);
  }

  for (int ct = 0; ct < NT; ct++) {
    // write staged regs to LDS (swizzled: byte ^= ((row&7)<<4))
    if constexpr (K == 128) {
      unsigned x = (unsigned)t * 16;
      unsigned d = x ^ (((x >> RS) & 7u) << 4);
      *(uint4*)(bbuf + d) = rh;
      *(uint4*)(bbuf + PLANE + d) = rl;
    } else {
      if (t < 128) {
        unsigned x = (unsigned)t * 16;
        unsigned d = x ^ (((x >> RS) & 7u) << 4);
        *(uint4*)(bbuf + d) = rh;
      } else {
        unsigned x = (unsigned)(t - 128) * 16;
        unsigned d = x ^ (((x >> RS) & 7u) << 4);
        *(uint4*)(bbuf + PLANE + d) = rl;
      }
    }
    __syncthreads();
    // prefetch next ct's B into regs — hides global latency under compute
    if (ct + 1 < NT) {
      if constexpr (K == 128) {
        rh = *(const uint4*)(gBhi + (size_t)(ct + 1) * PLANE + t * 16);
        rl = *(const uint4*)(gBlo + (size_t)(ct + 1) * PLANE + t * 16);
      } else {
        if (t < 128) rh = *(const uint4*)(gBhi + (size_t)(ct + 1) * PLANE + t * 16);
        else         rl = *(const uint4*)(gBlo + (size_t)(ct + 1) * PLANE + (t - 128) * 16);
      }
    }
    // read B fragments from LDS (swizzled)
    s8v bhi[K / 32], blo[K / 32];
#pragma unroll
    for (int kk = 0; kk < K / 32; kk++) {
      unsigned off = (unsigned)(q * 16 + kk * 64);
      unsigned ad = ((unsigned)r << RS) + (off ^ (((unsigned)(r & 7)) << 4));
      bhi[kk] = *(const s8v*)(bbuf + ad);
      blo[kk] = *(const s8v*)(bbuf + PLANE + ad);
    }
    int col = ct * 16 + r;
    float cmwv = 0.f;
    if constexpr (CMW) cmwv = cmw[col];
#pragma unroll
    for (int rr = 0; rr < R; rr++) {
      if (!valid[rr]) continue;
      f4v acc = {0.f, 0.f, 0.f, 0.f};
#pragma unroll
      for (int kk = 0; kk < K / 32; kk++) {
        acc = __builtin_amdgcn_mfma_f32_16x16x32_bf16(afrag[rr][kk], bhi[kk], acc, 0, 0, 0);
        acc = __builtin_amdgcn_mfma_f32_16x16x32_bf16(afrag[rr][kk], blo[kk], acc, 0, 0, 0);
      }
      int row0 = (tile0 + rr) * 16 + q * 4;
#pragma unroll
      for (int i = 0; i < 4; i++) {
        float v = acc[i] - cmwv;
        size_t row = (size_t)(row0 + i);
        if (col < BF) {
          feat8[row * BF + col] = f2fp8(v);
        } else if (col < BF + H) {
          el[row * H + (col - BF)] = v;
        } else if (col < BF + 2 * H) {
          er[row * H + (col - BF - H)] = v;
        } else if (RES0 < M && col >= RES0) {
          resh[row * (M - RES0) + (col - RES0)] = f2h(v);
        }
      }
    }
    __syncthreads();   // all reads of bbuf done before next ct's ds_write
  }
}

// ---------------- fused single-pass aggregation H=4 (fp8 feat table) ----------------
// MLP=16 structure + pipelined el-gather AND sj-batch: both of next chunk's serial
// load rounds issue during this chunk's FMA phase.
template <int MODE>
__global__ __launch_bounds__(256) void aggregate4(const unsigned char* __restrict__ feat8,
                                                  const float* __restrict__ el4,
                                                  const float* __restrict__ er4,
                                                  const int* __restrict__ csr_src,
                                                  const int* __restrict__ rsp,
                                                  const int* __restrict__ counts,
                                                  const unsigned short* __restrict__ resh,
                                                  unsigned short* __restrict__ vbf,
                                                  float* __restrict__ rnrm, int Nn) {
  int n = (int)((blockIdx.x * blockDim.x + threadIdx.x) >> 6);
  if (n >= Nn) return;
  int lane = threadIdx.x & 63;
  int start = __builtin_amdgcn_readfirstlane(rsp[n]);
  int deg = __builtin_amdgcn_readfirstlane(counts[n]);
  int chunks = (deg + 15) >> 4;
  int slot = lane >> 2, h = lane & 3;
  float ern = er4[(size_t)n * 4 + h];
  int hl = lane >> 4;                        // head of lane's dims (dims 2l..2l+1)
  unsigned dby = (unsigned)lane << 1;        // byte offset into 128B fp8 row
  f2v a01 = {0.f, 0.f};
  float dsum = 0.f;
  // prologue: chunk 0's sj batch + phase-A gather
  const int* csp0 = csr_src + start;
  int sj[16];
#pragma unroll
  for (int j = 0; j < 16; j++) sj[j] = csp0[j];
  float elv = el4[(size_t)csp0[slot] * 4 + h];
  for (int c = 0; c < chunks; c++) {
    float e = elv + ern;
    float exv = (((c << 4) + slot) < deg) ? __expf(fmaxf(e, 0.2f * e)) : 0.f;
    dsum += exv;
    // prefetch next chunk's batch + gather — in flight during this chunk's FMAs
    int sjn[16];
    bool more = (c + 1 < chunks);
    if (more) {
      const int* csp1 = csr_src + start + ((c + 1) << 4);
#pragma unroll
      for (int j = 0; j < 16; j++) sjn[j] = csp1[j];
      elv = el4[(size_t)csp1[slot] * 4 + h];
    }
#pragma unroll
    for (int j = 0; j < 16; j++) {
      float aw = __shfl(exv, (j << 2) | hl);
      unsigned short u = *(const unsigned short*)(feat8 + (((unsigned)sj[j] << 7) + dby));
      f2v fv = __builtin_amdgcn_cvt_pk_f32_fp8((int)u, false);
      f2v aw2 = {aw, aw};
      a01 = __builtin_elementwise_fma(fv, aw2, a01);
    }
    if (more) {
#pragma unroll
      for (int j = 0; j < 16; j++) sj[j] = sjn[j];
    }
  }
#pragma unroll
  for (int off = 4; off < 64; off <<= 1) dsum += __shfl_xor(dsum, off);
  float inv = dsum > 0.f ? 1.f / dsum : 0.f;
  float invh = __shfl(inv, hl);
  float v0, v1;
  if (MODE == 1) {
    h2 rr = *(const h2*)(resh + (size_t)n * 128 + lane * 2);
    v0 = elu1(elu1(a01[0] * invh + (float)rr[0]));
    v1 = elu1(elu1(a01[1] * invh + (float)rr[1]));
  } else {
    v0 = elu1(a01[0] * invh);
    v1 = elu1(a01[1] * invh);
  }
  float ss = v0 * v0 + v1 * v1;
#pragma unroll
  for (int off = 1; off < 64; off <<= 1) ss += __shfl_xor(ss, off);
  float rn = sqrtf(1e-6f + ss);
  float ri = 1.f / rn;
  unsigned int pk = (unsigned int)f2bf(v0 * ri) | ((unsigned int)f2bf(v1 * ri) << 16);
  *(unsigned int*)((char*)vbf + ((size_t)n << 8) + (lane << 2)) = pk;
  if (lane == 0) rnrm[n] = rn;
}

// ---------------- fused single-pass aggregation H=1 (layer 2, fp8 table) ----------------
__global__ __launch_bounds__(256) void aggregate1(const unsigned char* __restrict__ feat8,
                                                  const float* __restrict__ el1,
                                                  const float* __restrict__ er1,
                                                  const int* __restrict__ csr_src,
                                                  const int* __restrict__ rsp,
                                                  const int* __restrict__ counts,
                                                  const unsigned short* __restrict__ res2h,
                                                  float* __restrict__ out2, int Nn) {
  int n = (int)((blockIdx.x * blockDim.x + threadIdx.x) >> 6);
  if (n >= Nn) return;
  int lane = threadIdx.x & 63;
  int start = __builtin_amdgcn_readfirstlane(rsp[n]);
  int deg = __builtin_amdgcn_readfirstlane(counts[n]);
  int chunks = (deg + 15) >> 4;
  int l16 = lane & 15;
  float ern = er1[n];
  int g = lane >> 3;                          // 8 edge groups (2 edges each per chunk)
  unsigned dofs4 = (unsigned)(lane & 7) << 2; // byte offset into 32B fp8 row
  f2v acc01 = {0.f, 0.f}, acc23 = {0.f, 0.f};
  float dsum = 0.f;
  int sA = csr_src[start + l16];
  float elv = el1[sA];
  for (int c = 0; c < chunks; c++) {
    const int* csp = csr_src + start + (c << 4);
    float exv = (((c << 4) + l16) < deg) ? __expf(lrelu(elv + ern)) : 0.f;
    dsum += exv;
    int sAc = sA;
    if (c + 1 < chunks) {
      sA = csp[16 + l16];
      elv = el1[sA];
    }
#pragma unroll
    for (int t = 0; t < 2; t++) {
      int j = (t << 3) + g;
      int sj = __shfl(sAc, j);
      float aw = __shfl(exv, j);
      f2v aw2 = {aw, aw};
      unsigned int u = *(const unsigned int*)(feat8 + (((unsigned)sj << 5) + dofs4));
      f2v fa = __builtin_amdgcn_cvt_pk_f32_fp8((int)u, false);
      f2v fb = __builtin_amdgcn_cvt_pk_f32_fp8((int)u, true);
      acc01 = __builtin_elementwise_fma(fa, aw2, acc01);
      acc23 = __builtin_elementwise_fma(fb, aw2, acc23);
    }
  }
#pragma unroll
  for (int off = 1; off < 16; off <<= 1) dsum += __shfl_xor(dsum, off);
  float inv = dsum > 0.f ? 1.f / dsum : 0.f;
#pragma unroll
  for (int off = 8; off < 64; off <<= 1) {
    acc01[0] += __shfl_xor(acc01[0], off);
    acc01[1] += __shfl_xor(acc01[1], off);
    acc23[0] += __shfl_xor(acc23[0], off);
    acc23[1] += __shfl_xor(acc23[1], off);
  }
  if (lane < 8) {
    h4 rr = *(const h4*)(res2h + (size_t)n * 32 + (lane << 2));
    float4 o;
    o.x = acc01[0] * inv + (float)rr[0];
    o.y = acc01[1] * inv + (float)rr[1];
    o.z = acc23[0] * inv + (float)rr[2];
    o.w = acc23[1] * inv + (float)rr[3];
    *(float4*)(out2 + (size_t)n * 32 + (lane << 2)) = o;
  }
}

// ---------------- colsum of raw v = vbf * rnrm (packed-uint loads) ----------------
__global__ __launch_bounds__(256) void colsum_k(const unsigned short* __restrict__ vbf,
                                                const float* __restrict__ rnrm,
                                                float* __restrict__ colsum, int Nn) {
  __shared__ float2 ls[256];
  int tid = threadIdx.x;
  int c2 = tid & 63;        // cols 2*c2, 2*c2+1
  int rsub = tid >> 6;      // 4 rows per iter
  float2 cs = {0.f, 0.f};
  for (int r = blockIdx.x * 4 + rsub; r < Nn; r += gridDim.x * 4) {
    unsigned u = *(const unsigned*)(vbf + (size_t)r * 128 + c2 * 2);
    float rn = rnrm[r];
    cs.x += bf2f((unsigned short)(u & 0xffffu)) * rn;
    cs.y += bf2f((unsigned short)(u >> 16)) * rn;
  }
  ls[tid] = cs;
  __syncthreads();
  if (tid < 64) {
    float2 a = ls[tid], b = ls[tid + 64], c = ls[tid + 128], d = ls[tid + 192];
    atomicAdd(&colsum[2 * tid], a.x + b.x + c.x + d.x);
    atomicAdd(&colsum[2 * tid + 1], a.y + b.y + c.y + d.y);
  }
}

// ---------------- final: mean over nodes of out2 ----------------
__global__ __launch_bounds__(256) void final_reduce(const float* __restrict__ out2,
                                                    float* __restrict__ outsum, int Nn) {
  __shared__ float ls[32];
  if (threadIdx.x < 32) ls[threadIdx.x] = 0.f;
  __syncthreads();
  int d = threadIdx.x & 31, rl = threadIdx.x >> 5;
  float acc = 0.f;
  for (int n = blockIdx.x * 8 + rl; n < Nn; n += gridDim.x * 8)
    acc += out2[(size_t)n * 32 + d];
  atomicAdd(&ls[d], acc);
  __syncthreads();
  if (threadIdx.x < 32) atomicAdd(&outsum[threadIdx.x], ls[threadIdx.x]);
}

__global__ void finalize_k(const float* __restrict__ outsum, float* __restrict__ out, float invN) {
  int t = threadIdx.x;
  if (t < 32) out[t] = outsum[t] * invN;
}

// ---------------- launcher ----------------
extern "C" void kernel_launch(void* const* d_in, const int* in_sizes, int n_in,
                              void* d_out, int out_size, void* d_ws, size_t ws_size,
                              hipStream_t stream) {
  const float* x     = (const float*)d_in[0];
  const int*   src   = (const int*)d_in[1];
  const int*   dst   = (const int*)d_in[2];
  const float* W0    = (const float*)d_in[3];
  const float* al0   = (const float*)d_in[4];
  const float* ar0   = (const float*)d_in[5];
  const float* W1    = (const float*)d_in[6];
  const float* al1   = (const float*)d_in[7];
  const float* ar1   = (const float*)d_in[8];
  const float* resW1 = (const float*)d_in[9];
  const float* W2    = (const float*)d_in[10];
  const float* al2   = (const float*)d_in[11];
  const float* ar2   = (const float*)d_in[12];
  const float* resW2 = (const float*)d_in[13];
  const int N = in_sizes[0] / 64;   // 100000
  const int E = in_sizes[1];        // 1600000
  const float invN = 1.f / (float)N;
  const int Emax = E + 64;              // unpadded CSR + zeroed tail guard
  const int NB = (N + 255) >> 8;        // dst buckets of 256 nodes (391)
  const int P2B = 512;                  // histogram/scatter block count
  const int chunk = (((E + P2B - 1) / P2B) + 3) & ~3;  // multiple of 4 for int4 loads
  const int segN = NB * P2B;            // bucket-major segment table length
  const int nbB = (segN + 1023) / 1024; // scan blocks for segment table (196)

  char* p = (char*)d_ws;
  auto alloc = [&](size_t bytes) { char* r = p; p += (bytes + 255) & ~(size_t)255; return r; };

  // zero-initialized region (small: reduction accumulators only)
  char* zbase = p;
  float* colsumA = (float*)alloc(512);
  float* colsumB = (float*)alloc(512);
  float* outsum  = (float*)alloc(128);
  size_t zbytes = (size_t)(p - zbase);

  int* counts = (int*)alloc((size_t)4 * N);     // written by fscatter
  int* rsp    = (int*)alloc((size_t)4 * N);     // written by fscatter (unpadded row starts)
  int* bsumB  = (int*)alloc(1024);
  int* bhist  = (int*)alloc((size_t)4 * segN);  // per-(bucket,block) counts -> per-1024-block scan
  unsigned int* ebuf = (unsigned int*)alloc((size_t)4 * E);  // packed (src<<8)|(dst&255)
  int* csr_src = (int*)alloc((size_t)4 * Emax);
  unsigned char*  feat8 = (unsigned char*)alloc((size_t)N * 128);     // fp8 gather table
  unsigned short* vbf   = (unsigned short*)alloc((size_t)2 * N * 128);
  unsigned short* resh  = (unsigned short*)alloc((size_t)2 * N * 128);  // f16 residuals
  unsigned short* w0t = (unsigned short*)alloc((size_t)2 * 2 * 144 * 64);
  unsigned short* w1t = (unsigned short*)alloc((size_t)2 * 2 * 272 * 128);
  unsigned short* w2t = (unsigned short*)alloc((size_t)2 * 2 * 80 * 128);
  float* el4  = (float*)alloc((size_t)16 * N);
  float* er4  = (float*)alloc((size_t)16 * N);
  float* rnrm = (float*)alloc((size_t)4 * N);
  float* cmw1 = (float*)alloc(4 * 272);
  float* cmw2 = (float*)alloc(4 * 80);
  float* out2 = (float*)alloc((size_t)4 * N * 32);   // layer-2 output [N][32]

  hipMemsetAsync(zbase, 0, zbytes, stream);
  hipMemsetAsync(csr_src + E, 0, (size_t)4 * (Emax - E), stream);  // tail guard only

  // CSR build + weight pack (pscan2 eliminated: prefix re-derived in consumers)
  const int packTot = 144 * 64 + 272 * 128 + 80 * 128;   // 54272
  const int packBlocks = (packTot + 255) / 256;          // 212
  hist_pack_k<<<P2B + packBlocks, 256, 0, stream>>>(dst, bhist, E, NB, chunk, P2B,
                                                    W0, al0, ar0, W1, al1, ar1, resW1,
                                                    W2, al2, ar2, resW2, w0t, w1t, w2t);
  pscan1<<<nbB, 256, 0, stream>>>(bhist, bsumB, segN);
  bscatter_k<<<P2B, 256, 0, stream>>>(src, dst, bhist, bsumB, ebuf, E, NB, chunk, nbB);
  fscatter_k<<<NB, 256, 0, stream>>>(ebuf, bhist, bsumB, csr_src, counts, rsp, E, NB, P2B, N, nbB);

  const int rowTiles = N / 16;                   // 6250
  const int gblocks = (rowTiles + 7) / 8;        // 4 waves x R=2 tiles = 8 tiles/block
  const int aggblocks = (N + 3) / 4;             // wave per node

  // Layer 0 (A = x fp32, no colmean fold)
  gemm_bf16<64, 144, 2, 128, 4, 144, true, false><<<gblocks, 256, 0, stream>>>(
      x, w0t, nullptr, feat8, el4, er4, nullptr, rowTiles);
  aggregate4<0><<<aggblocks, 256, 0, stream>>>(feat8, el4, er4, csr_src, rsp, counts, nullptr, vbf, rnrm, N);
  colsum_k<<<512, 256, 0, stream>>>(vbf, rnrm, colsumA, N);
  cmw_k<<<2, 256, 0, stream>>>(colsumA, w1t, cmw1, 128, 272, invN);

  // Layer 1 (A = vbf, colmean via cmw1)
  gemm_bf16<128, 272, 2, 128, 4, 144, false, true><<<gblocks, 256, 0, stream>>>(
      vbf, w1t, cmw1, feat8, el4, er4, resh, rowTiles);
  aggregate4<1><<<aggblocks, 256, 0, stream>>>(feat8, el4, er4, csr_src, rsp, counts, resh, vbf, rnrm, N);
  colsum_k<<<512, 256, 0, stream>>>(vbf, rnrm, colsumB, N);
  cmw_k<<<1, 256, 0, stream>>>(colsumB, w2t, cmw2, 128, 80, invN);

  // Layer 2 (A = vbf, colmean via cmw2)
  gemm_bf16<128, 80, 2, 32, 1, 48, false, true><<<gblocks, 256, 0, stream>>>(
      vbf, w2t, cmw2, feat8, el4, er4, resh, rowTiles);
  aggregate1<<<aggblocks, 256, 0, stream>>>(feat8, el4, er4, csr_src, rsp, counts, resh, out2, N);
  final_reduce<<<512, 256, 0, stream>>>(out2, outsum, N);
  finalize_k<<<1, 64, 0, stream>>>(outsum, (float*)d_out, invN);
}